// Round 5
// baseline (573.209 us; speedup 1.0000x reference)
//
#include <hip/hip_runtime.h>
#include <hip/hip_cooperative_groups.h>
namespace cg = cooperative_groups;

// SelfAttentiveLBLBiLM on MI355X — round 12.
// r11 post-mortem: QKV FETCH 37->32.7MB but time flat; attn 4-row flat.
// Accounting: sum of modeled kernel times ~115us vs 236 measured, no hidden
// dispatch >43.8us possible (top-5 cutoff) -> ~120us lives in launch gaps
// and/or several mid-size kernels. Both attacked at once: attn+proj+hw1+hw2
// fused into ONE cooperative kernel (256 blocks x 512 thr, 128KB LDS ->
// exactly co-resident at 1 block/CU) with grid.sync() between phases.
//  - attn phase: 4-row waves, 2 reps (dir=0,1)
//  - proj phase: two virtual 128^2 blocks per physical (waves 0-3/4-7,
//    disjoint 35KB LDS halves, identical barrier schedules)
//  - hw phase: proven 256^2 8-phase body, layer loop with grid sync
// Dispatches: prep, qkv gemm(128^2+XCD swz), mega. 6 -> 3 launches.

#define B_ 8
#define S_ 1024
#define D_ 512
#define H_ 8
#define DK_ 64
#define WIDTH_ 8
#define S2_ 1040
#define NHW_ 2

typedef short bf16x8 __attribute__((ext_vector_type(8)));
typedef float f32x4 __attribute__((ext_vector_type(4)));

__device__ __forceinline__ float us2f(unsigned short u) {
  union { unsigned int i; float f; } c; c.i = ((unsigned int)u) << 16; return c.f;
}
__device__ __forceinline__ unsigned short f2us(float f) {
  union { float f; unsigned int i; } c; c.f = f;
  unsigned int x = c.i;
  return (unsigned short)((x + 0x7fffu + ((x >> 16) & 1u)) >> 16);
}
__device__ __forceinline__ unsigned int pack2(float a, float b) {
  return (unsigned int)f2us(a) | ((unsigned int)f2us(b) << 16);
}
__device__ __forceinline__ void async16(const void* g, void* l) {
  __builtin_amdgcn_global_load_lds(
      (const __attribute__((address_space(1))) void*)g,
      (__attribute__((address_space(3))) void*)l, 16, 0, 0);
}
__device__ __forceinline__ void unpack8(uint4 u, float* f) {
  unsigned int w[4] = {u.x, u.y, u.z, u.w};
  #pragma unroll
  for (int c = 0; c < 4; ++c) {
    union { unsigned int i; float g; } lo, hi;
    lo.i = w[c] << 16;
    hi.i = w[c] & 0xffff0000u;
    f[2 * c] = lo.g;
    f[2 * c + 1] = hi.g;
  }
}

// ---------------------------------------------------------------------------
// Prep mega-kernel (unchanged from r11).
__global__ __launch_bounds__(256) void k_prep(
    const float* __restrict__ x,
    const float* __restrict__ lpad, const float* __restrict__ rpad,
    const float* __restrict__ lW, const float* __restrict__ rW,
    const float* __restrict__ lb, const float* __restrict__ rb,
    const float* __restrict__ lhwW, const float* __restrict__ rhwW,
    unsigned short* __restrict__ WTall, unsigned short* __restrict__ WTp,
    unsigned short* __restrict__ hWT,
    unsigned short* __restrict__ nin, float* __restrict__ qkvbias)
{
  __shared__ float tile[32][33];
  const size_t DD = (size_t)D_ * D_;
  int bx = blockIdx.x;
  int tx = threadIdx.x & 31, ty = threadIdx.x >> 5;

  if (bx < 2048) {                     // ---- attn transpose
    int sl = bx >> 8, rem = bx & 255;
    int side = sl >> 2, slice = sl & 3;
    int c0 = (rem & 15) * 32, r0 = (rem >> 4) * 32;
    const float* src = (side ? rW : lW) + (size_t)slice * DD;
    unsigned short* dst = (slice < 3) ? WTall + (size_t)(side * 3 + slice) * DD
                                      : WTp + (size_t)side * DD;
    #pragma unroll
    for (int i = 0; i < 4; ++i)
      tile[ty + i * 8][tx] = src[(size_t)(r0 + ty + i * 8) * D_ + c0 + tx];
    __syncthreads();
    #pragma unroll
    for (int i = 0; i < 4; ++i)
      dst[(size_t)(c0 + ty + i * 8) * D_ + r0 + tx] = f2us(tile[tx][ty + i * 8]);
    return;
  }
  if (bx < 4096) {                     // ---- hw transpose + interleave
    int idx = bx - 2048;
    int sl = idx >> 9, rem = idx & 511;    // sl: side*2+layer
    int c0 = (rem & 31) * 32, r0 = (rem >> 5) * 32;
    const float* src = ((sl >> 1) ? rhwW : lhwW) + (size_t)(sl & 1) * 512 * 1024;
    unsigned short* dst = hWT + (size_t)sl * 1024 * 512;
    #pragma unroll
    for (int i = 0; i < 4; ++i)
      tile[ty + i * 8][tx] = src[(size_t)(r0 + ty + i * 8) * 1024 + c0 + tx];
    __syncthreads();
    #pragma unroll
    for (int i = 0; i < 4; ++i) {
      int c = c0 + ty + i * 8;
      int cm = c & 511;
      int j = cm >> 4;
      int jl = j & 7;
      int Bq = ((jl >> 2) << 3) + (jl & 3) + ((c >= 512) ? 4 : 0);
      int q = (j >> 3) * 256 + Bq * 16 + (cm & 15);
      dst[(size_t)q * 512 + r0 + tx] = f2us(tile[tx][ty + i * 8]);
    }
    return;
  }
  // ---- build new_in + bias tail
  int gid = (bx - 4096) * 256 + threadIdx.x;
  const int NTH = B_ * S2_ * 64;       // 532,480
  if (gid >= NTH) {
    int t = gid - NTH;
    if (t < 1536) qkvbias[t] = lb[t];
    else if (t < 3072) qkvbias[t] = rb[t - 1536];
    return;
  }
  int c8 = (gid & 63) << 3;
  int row = gid >> 6;
  int b = row / S2_;
  int t = row - b * S2_;
  const float* src;
  if (t < WIDTH_)            src = lpad + (size_t)t * D_ + c8;
  else if (t >= S_ + WIDTH_) src = rpad + (size_t)(t - S_ - WIDTH_) * D_ + c8;
  else                       src = x + ((size_t)b * S_ + (t - WIDTH_)) * D_ + c8;
  float4 a = *reinterpret_cast<const float4*>(src);
  float4 c = *reinterpret_cast<const float4*>(src + 4);
  uint4 o;
  o.x = pack2(a.x, a.y); o.y = pack2(a.z, a.w);
  o.z = pack2(c.x, c.y); o.w = pack2(c.z, c.w);
  *reinterpret_cast<uint4*>(nin + (size_t)row * D_ + c8) = o;
}

// ---------------------------------------------------------------------------
// MFMA GEMM (QKV): 128^2 2-phase + XCD swizzle (unchanged from r11).
__global__ __launch_bounds__(256) void k_gemm_mfma(
    const unsigned short* __restrict__ A,
    const unsigned short* __restrict__ BT,
    const float* __restrict__ bias,
    unsigned short* __restrict__ C,
    int M, int N, int K)
{
  __shared__ unsigned short As[128 * 64];
  __shared__ unsigned short Bs[128 * 64];

  const int tid = threadIdx.x;
  const int w = tid >> 6;
  const int l = tid & 63;

  const int gx = gridDim.x;
  const int nwg = gx * gridDim.y;
  const int flat = blockIdx.y * gx + blockIdx.x;
  const int cpx = nwg >> 3;
  const int nf = (flat & 7) * cpx + (flat >> 3);
  const int bm = (nf / gx) * 128;
  const int bn = (nf % gx) * 128;

  const int wrow = (w >> 1) * 64;
  const int wcol = (w & 1) * 64;

  const int lr = l >> 3;
  const int sk = (((l & 7) ^ lr) & 7) * 8;
  const unsigned short* Ap = A + (size_t)(bm + w * 8 + lr) * K + sk;
  const unsigned short* Bp = BT + (size_t)(bn + w * 8 + lr) * K + sk;
  unsigned short* lA = &As[w * 512];
  unsigned short* lB = &Bs[w * 512];
  const size_t K32 = (size_t)32 * K;

  const int fl = l & 15;
  const int fq = l >> 4;
  const int fx = fl & 7;

  f32x4 acc[4][4];
  #pragma unroll
  for (int mi = 0; mi < 4; ++mi)
    #pragma unroll
    for (int ni = 0; ni < 4; ++ni) acc[mi][ni] = (f32x4){0.f, 0.f, 0.f, 0.f};

  for (int k0 = 0; k0 < K; k0 += 64) {
    #pragma unroll
    for (int r = 0; r < 4; ++r) {
      async16(Ap + k0 + r * K32, lA + r * 2048);
      async16(Bp + k0 + r * K32, lB + r * 2048);
    }
    __syncthreads();
    #pragma unroll
    for (int s = 0; s < 2; ++s) {
      bf16x8 af[4], bfr[4];
      #pragma unroll
      for (int mi = 0; mi < 4; ++mi)
        af[mi] = *reinterpret_cast<const bf16x8*>(
            &As[(wrow + mi * 16 + fl) * 64 + (((s * 4 + fq) ^ fx) * 8)]);
      #pragma unroll
      for (int ni = 0; ni < 4; ++ni)
        bfr[ni] = *reinterpret_cast<const bf16x8*>(
            &Bs[(wcol + ni * 16 + fl) * 64 + (((s * 4 + fq) ^ fx) * 8)]);
      #pragma unroll
      for (int mi = 0; mi < 4; ++mi)
        #pragma unroll
        for (int ni = 0; ni < 4; ++ni)
          acc[mi][ni] = __builtin_amdgcn_mfma_f32_16x16x32_bf16(
              af[mi], bfr[ni], acc[mi][ni], 0, 0, 0);
    }
    __syncthreads();
  }

  float bv[4];
  #pragma unroll
  for (int ni = 0; ni < 4; ++ni) bv[ni] = bias[bn + wcol + ni * 16 + fl];

  const int rbase = (l >> 4) * 4;
  #pragma unroll
  for (int mi = 0; mi < 4; ++mi) {
    #pragma unroll
    for (int r = 0; r < 4; ++r) {
      int row = bm + wrow + mi * 16 + rbase + r;
      unsigned short* Cp = C + (size_t)row * N + bn + wcol + fl;
      #pragma unroll
      for (int ni = 0; ni < 4; ++ni)
        Cp[ni * 16] = f2us(acc[mi][ni][r] + bv[ni]);
    }
  }
}

// ---------------------------------------------------------------------------
// hw layer body: 256^2 8-phase GEMM + gate epilogue (from k_gemm256, proven
// r9-r11). A/BT/bias pre-offset for (z,lay). Obf pre-offset z*MS; Ofp z*512.
__device__ __forceinline__ void hw_layer(
    unsigned short* smem,
    const unsigned short* __restrict__ A,
    const unsigned short* __restrict__ BT,
    const float* __restrict__ bias,
    unsigned short* __restrict__ Obf,
    float* __restrict__ Ofp,
    int bx, int by, bool final_)
{
  const int tid = threadIdx.x;
  const int w = tid >> 6, l = tid & 63;
  const int wm = w >> 2, wn = w & 3;
  const int fl = l & 15, fq = l >> 4;
  const int bm = by * 256, bn = bx * 256;

  const int xorb = (fl & 7) << 4;
  const int cs0 = ((fq * 16) ^ xorb) >> 1;
  const int cs1 = ((64 + fq * 16) ^ xorb) >> 1;

  const int rr = l >> 3;
  const int ce = (((l & 7) * 16) ^ (rr << 4)) >> 1;
  const unsigned short* gA[2][2];
  const unsigned short* gB[2][2];
  #pragma unroll
  for (int i = 0; i < 2; ++i)
    #pragma unroll
    for (int h = 0; h < 2; ++h) {
      int ra = bm + h * 128 + (2 * w + i) * 8 + rr;
      gA[i][h] = A + (size_t)ra * 512 + ce;
      int rb = bn + h * 128 + (2 * w + i) * 8 + rr;
      gB[i][h] = BT + (size_t)rb * 512 + ce;
    }

  f32x4 acc[8][4];
  #pragma unroll
  for (int mi = 0; mi < 8; ++mi)
    #pragma unroll
    for (int ni = 0; ni < 4; ++ni) acc[mi][ni] = (f32x4){0.f, 0.f, 0.f, 0.f};

  bf16x8 ar[4][2], br[2][2];

#define BAR() __builtin_amdgcn_s_barrier()
#define STGA(buf, h, kt) do { \
    async16(gA[0][h] + (kt) * 64, &smem[((buf) * 2 + (h)) * 8192 + (2 * w) * 512]); \
    async16(gA[1][h] + (kt) * 64, &smem[((buf) * 2 + (h)) * 8192 + (2 * w + 1) * 512]); } while (0)
#define STGB(buf, h, kt) do { \
    async16(gB[0][h] + (kt) * 64, &smem[32768 + ((buf) * 2 + (h)) * 8192 + (2 * w) * 512]); \
    async16(gB[1][h] + (kt) * 64, &smem[32768 + ((buf) * 2 + (h)) * 8192 + (2 * w + 1) * 512]); } while (0)
#define LDA(buf, h) do { const unsigned short* p_ = &smem[((buf) * 2 + (h)) * 8192]; \
    _Pragma("unroll") for (int m4 = 0; m4 < 4; ++m4) { \
      int ro_ = ((2 * m4 + wm) * 16 + fl) * 64; \
      ar[m4][0] = *reinterpret_cast<const bf16x8*>(p_ + ro_ + cs0); \
      ar[m4][1] = *reinterpret_cast<const bf16x8*>(p_ + ro_ + cs1); } } while (0)
#define LDB(buf, h) do { const unsigned short* p_ = &smem[32768 + ((buf) * 2 + (h)) * 8192]; \
    _Pragma("unroll") for (int n2 = 0; n2 < 2; ++n2) { \
      int ro_ = ((4 * n2 + wn) * 16 + fl) * 64; \
      br[n2][0] = *reinterpret_cast<const bf16x8*>(p_ + ro_ + cs0); \
      br[n2][1] = *reinterpret_cast<const bf16x8*>(p_ + ro_ + cs1); } } while (0)
#define QUAD(miH, niH) do { __builtin_amdgcn_s_setprio(1); \
    _Pragma("unroll") for (int m4 = 0; m4 < 4; ++m4) \
      _Pragma("unroll") for (int n2 = 0; n2 < 2; ++n2) \
        _Pragma("unroll") for (int s_ = 0; s_ < 2; ++s_) \
          acc[(miH) * 4 + m4][(niH) * 2 + n2] = __builtin_amdgcn_mfma_f32_16x16x32_bf16( \
              ar[m4][s_], br[n2][s_], acc[(miH) * 4 + m4][(niH) * 2 + n2], 0, 0, 0); \
    __builtin_amdgcn_s_setprio(0); } while (0)

  STGA(0, 0, 0); STGB(0, 0, 0); STGB(0, 1, 0); STGA(0, 1, 0);
  STGA(1, 0, 1); STGB(1, 1, 1); STGA(1, 1, 1);
  asm volatile("s_waitcnt vmcnt(6)" ::: "memory");
  BAR();

  #pragma unroll 1
  for (int it = 0; it < 4; ++it) {
    const int t1 = 2 * it + 1, t2 = 2 * it + 2, t3 = 2 * it + 3;
    LDA(0, 0); LDB(0, 0);
    STGB(1, 0, t1);
    BAR(); QUAD(0, 0); BAR();
    LDB(0, 1);
    if (t2 < 8) STGA(0, 0, t2);
    BAR(); QUAD(0, 1); BAR();
    LDA(0, 1);
    if (t2 < 8) STGB(0, 1, t2);
    BAR(); QUAD(1, 1); BAR();
    LDB(0, 0);
    if (t2 < 8) STGA(0, 1, t2);
    BAR(); QUAD(1, 0);
    if (it < 3) asm volatile("s_waitcnt vmcnt(6)" ::: "memory");
    else        asm volatile("s_waitcnt vmcnt(0)" ::: "memory");
    BAR();
    LDA(1, 0); LDB(1, 0);
    if (t2 < 8) STGB(0, 0, t2);
    BAR(); QUAD(0, 0); BAR();
    LDB(1, 1);
    if (t3 < 8) STGA(1, 0, t3);
    BAR(); QUAD(0, 1); BAR();
    LDA(1, 1);
    if (t3 < 8) STGB(1, 1, t3);
    BAR(); QUAD(1, 1); BAR();
    LDB(1, 0);
    if (t3 < 8) STGA(1, 1, t3);
    BAR(); QUAD(1, 0);
    asm volatile("s_waitcnt vmcnt(6)" ::: "memory");
    BAR();
  }
#undef BAR
#undef STGA
#undef STGB
#undef LDA
#undef LDB
#undef QUAD

  float bnl[2], bg[2]; int xs[2];
  #pragma unroll
  for (int np = 0; np < 2; ++np) {
    xs[np] = (bx * 8 + np * 4 + wn) * 16 + fl;
    bnl[np] = bias[xs[np]];
    bg[np]  = bias[512 + xs[np]];
  }
  #pragma unroll
  for (int mi = 0; mi < 8; ++mi) {
    #pragma unroll
    for (int r = 0; r < 4; ++r) {
      int gr = bm + (2 * mi + wm) * 16 + fq * 4 + r;
      #pragma unroll
      for (int np = 0; np < 2; ++np) {
        float nl = fmaxf(acc[mi][2 * np][r] + bnl[np], 0.f);
        float g  = 1.f / (1.f + __expf(-(acc[mi][2 * np + 1][r] + bg[np])));
        float xv = us2f(A[(size_t)gr * 512 + xs[np]]);
        float res = g * xv + (1.f - g) * nl;
        if (final_) Ofp[(size_t)gr * 1024 + xs[np]] = res;
        else        Obf[(size_t)gr * 512 + xs[np]] = f2us(res);
      }
    }
  }
}

// ---------------------------------------------------------------------------
// Mega cooperative kernel: attn -> proj+rel -> hw x2. 256 blocks x 512 thr,
// 128KB LDS (1 block/CU, exactly co-resident). grid.sync between phases.
__global__ __launch_bounds__(512, 2) void k_mega(
    const unsigned short* __restrict__ qkv,
    unsigned short* __restrict__ ctx,
    const unsigned short* __restrict__ WTp,
    const unsigned short* __restrict__ nin,
    const float* __restrict__ lb3, const float* __restrict__ rb3,
    const float* __restrict__ wrel0, const float* __restrict__ wrel1,
    unsigned short* __restrict__ hwx,
    unsigned short* __restrict__ hwy,
    const unsigned short* __restrict__ hWT,
    const float* __restrict__ lhwb, const float* __restrict__ rhwb,
    float* __restrict__ out)
{
  __shared__ __align__(16) unsigned short smem[65536];   // 128 KiB
  cg::grid_group grid = cg::this_grid();
  const size_t MS = (size_t)B_ * S_ * D_;
  const size_t LHW = (size_t)1024 * 512;

  // ================= Phase A: windowed attention =================
  {
    const int lane = threadIdx.x & 63;
    const int wv = blockIdx.x * 8 + (threadIdx.x >> 6);   // 0..2047
    const int c0 = lane * 8;
    const int sg = wv & 255;
    const int b = (wv >> 8) & 7;
    const int s0 = sg << 2;
    const int i0 = s0 + WIDTH_;

    #pragma unroll 1
    for (int dir = 0; dir < 2; ++dir) {
      const size_t base = (size_t)b * S2_ * 3072 + dir * 1536;

      float qf[4][8];
      #pragma unroll
      for (int r = 0; r < 4; ++r)
        unpack8(*reinterpret_cast<const uint4*>(
            qkv + base + (size_t)(i0 + r) * 3072 + c0), qf[r]);

      float sc[4][10];
      float mx[4] = {-1e30f, -1e30f, -1e30f, -1e30f};
      #pragma unroll
      for (int t = 0; t < 13; ++t) {
        int j = (dir == 0) ? (i0 - 9 + t) : (i0 + t);
        bool ok = (j >= 0 && j < S2_);
        float kf[8];
        if (ok)
          unpack8(*reinterpret_cast<const uint4*>(
              qkv + base + (size_t)j * 3072 + 512 + c0), kf);
        #pragma unroll
        for (int r = 0; r < 4; ++r) {
          if (t < r || t > r + 9) continue;
          float sv = -1e30f;
          if (ok) {
            float p = qf[r][0] * kf[0];
            #pragma unroll
            for (int e = 1; e < 8; ++e) p += qf[r][e] * kf[e];
            p += __shfl_xor(p, 1);
            p += __shfl_xor(p, 2);
            p += __shfl_xor(p, 4);
            sv = p * 0.125f;
          }
          sc[r][t - r] = sv;
          mx[r] = fmaxf(mx[r], sv);
        }
      }

      float inv[4];
      #pragma unroll
      for (int r = 0; r < 4; ++r) {
        float den = 0.f;
        #pragma unroll
        for (int u = 0; u < 10; ++u) {
          sc[r][u] = (sc[r][u] > -1e29f) ? __expf(sc[r][u] - mx[r]) : 0.f;
          den += sc[r][u];
        }
        inv[r] = 1.f / den;
      }

      float acc[4][8];
      #pragma unroll
      for (int r = 0; r < 4; ++r)
        #pragma unroll
        for (int e = 0; e < 8; ++e) acc[r][e] = 0.f;

      #pragma unroll
      for (int t = 0; t < 13; ++t) {
        int j = (dir == 0) ? (i0 - 9 + t) : (i0 + t);
        bool ok = (j >= 0 && j < S2_);
        float vf[8];
        if (ok)
          unpack8(*reinterpret_cast<const uint4*>(
              qkv + base + (size_t)j * 3072 + 1024 + c0), vf);
        #pragma unroll
        for (int r = 0; r < 4; ++r) {
          if (t < r || t > r + 9) continue;
          if (ok) {
            float p = sc[r][t - r];
            #pragma unroll
            for (int e = 0; e < 8; ++e) acc[r][e] += p * vf[e];
          }
        }
      }

      #pragma unroll
      for (int r = 0; r < 4; ++r) {
        uint4 o;
        o.x = pack2(acc[r][0] * inv[r], acc[r][1] * inv[r]);
        o.y = pack2(acc[r][2] * inv[r], acc[r][3] * inv[r]);
        o.z = pack2(acc[r][4] * inv[r], acc[r][5] * inv[r]);
        o.w = pack2(acc[r][6] * inv[r], acc[r][7] * inv[r]);
        *reinterpret_cast<uint4*>(
            ctx + (((size_t)dir * B_ + b) * S_ + s0 + r) * D_ + c0) = o;
      }
    }
  }
  __threadfence();
  grid.sync();

  // ================= Phase P: proj + fused rel-add =================
  // Two virtual 128^2 blocks per physical block: waves 0-3 (h=0), 4-7 (h=1).
  // Identical barrier schedules; disjoint 34.8KB LDS halves.
  {
    const int h = threadIdx.x >> 8;
    const int t2 = threadIdx.x & 255;
    const int v = blockIdx.x * 2 + h;            // 0..511
    const int bx = v & 3, by = (v >> 2) & 63, z = v >> 8;
    unsigned short* sm = smem + h * 17408;       // 128*136 shorts per half
    unsigned short* As = sm;
    unsigned short* Bs = sm + 8192;
    const int K = 512;
    const unsigned short* A = ctx + (size_t)z * MS;
    const unsigned short* BT = WTp + (size_t)z * 262144;
    const float* bias = z ? rb3 : lb3;
    const float* wrel = z ? wrel1 : wrel0;
    const int off = z * WIDTH_;

    const int w = t2 >> 6;
    const int l = t2 & 63;
    const int bm = by * 128;
    const int bn = bx * 128;
    const int wrow = (w >> 1) * 64;
    const int wcol = (w & 1) * 64;

    const int lr = l >> 3;
    const int sk = (((l & 7) ^ lr) & 7) * 8;
    const unsigned short* Ap = A + (size_t)(bm + w * 8 + lr) * K + sk;
    const unsigned short* Bp = BT + (size_t)(bn + w * 8 + lr) * K + sk;
    unsigned short* lA = &As[w * 512];
    unsigned short* lB = &Bs[w * 512];
    const size_t K32 = (size_t)32 * K;

    const int fl = l & 15;
    const int fq = l >> 4;
    const int fx = fl & 7;

    f32x4 acc[4][4];
    #pragma unroll
    for (int mi = 0; mi < 4; ++mi)
      #pragma unroll
      for (int ni = 0; ni < 4; ++ni) acc[mi][ni] = (f32x4){0.f, 0.f, 0.f, 0.f};

    for (int k0 = 0; k0 < K; k0 += 64) {
      #pragma unroll
      for (int r = 0; r < 4; ++r) {
        async16(Ap + k0 + r * K32, lA + r * 2048);
        async16(Bp + k0 + r * K32, lB + r * 2048);
      }
      __syncthreads();
      #pragma unroll
      for (int s = 0; s < 2; ++s) {
        bf16x8 af[4], bfr[4];
        #pragma unroll
        for (int mi = 0; mi < 4; ++mi)
          af[mi] = *reinterpret_cast<const bf16x8*>(
              &As[(wrow + mi * 16 + fl) * 64 + (((s * 4 + fq) ^ fx) * 8)]);
        #pragma unroll
        for (int ni = 0; ni < 4; ++ni)
          bfr[ni] = *reinterpret_cast<const bf16x8*>(
              &Bs[(wcol + ni * 16 + fl) * 64 + (((s * 4 + fq) ^ fx) * 8)]);
        #pragma unroll
        for (int mi = 0; mi < 4; ++mi)
          #pragma unroll
          for (int ni = 0; ni < 4; ++ni)
            acc[mi][ni] = __builtin_amdgcn_mfma_f32_16x16x32_bf16(
                af[mi], bfr[ni], acc[mi][ni], 0, 0, 0);
      }
      __syncthreads();
    }

    float bv[4];
    #pragma unroll
    for (int ni = 0; ni < 4; ++ni) bv[ni] = bias[bn + wcol + ni * 16 + fl];
    const int rbase = (l >> 4) * 4;
    #pragma unroll
    for (int mi = 0; mi < 4; ++mi)
      #pragma unroll
      for (int r = 0; r < 4; ++r)
        #pragma unroll
        for (int ni = 0; ni < 4; ++ni)
          sm[(wrow + mi * 16 + rbase + r) * 136 + wcol + ni * 16 + fl] =
              f2us(acc[mi][ni][r] + bv[ni]);
    __syncthreads();

    const int trow = t2 >> 4;
    const int tcol = (t2 & 15) * 8;
    const float wj[9] = {wrel[0], wrel[1], wrel[2], wrel[3], wrel[4],
                         wrel[5], wrel[6], wrel[7], wrel[8]};
    #pragma unroll
    for (int i = 0; i < 8; ++i) {
      int r = trow + i * 16;
      int gr = bm + r;
      int b = gr >> 10, s = gr & (S_ - 1);
      float a8[8];
      unpack8(*reinterpret_cast<const uint4*>(&sm[r * 136 + tcol]), a8);
      const unsigned short* np =
          nin + ((size_t)b * S2_ + off + s) * D_ + bn + tcol;
      #pragma unroll
      for (int j = 0; j < 9; ++j) {
        float nf[8];
        unpack8(*reinterpret_cast<const uint4*>(np + (size_t)j * D_), nf);
        #pragma unroll
        for (int e = 0; e < 8; ++e) a8[e] += wj[j] * nf[e];
      }
      uint4 o;
      o.x = pack2(a8[0], a8[1]); o.y = pack2(a8[2], a8[3]);
      o.z = pack2(a8[4], a8[5]); o.w = pack2(a8[6], a8[7]);
      *reinterpret_cast<uint4*>(
          hwx + (size_t)z * MS + (size_t)gr * D_ + bn + tcol) = o;
    }
  }
  __threadfence();
  grid.sync();

  // ================= Phase H: highway layers x2 =================
  {
    const int bx = blockIdx.x & 3;
    const int by = (blockIdx.x >> 2) & 31;
    const int z = blockIdx.x >> 7;
    #pragma unroll 1
    for (int lay = 0; lay < 2; ++lay) {
      const unsigned short* A  = (lay ? hwy : hwx) + (size_t)z * MS;
      const unsigned short* BT = hWT + ((size_t)(z * 2 + lay)) * LHW;
      const float* bias = (z ? rhwb : lhwb) + lay * 1024;
      hw_layer(smem, A, BT, bias,
               hwy + (size_t)z * MS,
               out + (size_t)z * 512,
               bx, by, lay == 1);
      if (lay == 0) { __threadfence(); grid.sync(); }
    }
  }
}

// ---------------------------------------------------------------------------
extern "C" void kernel_launch(void* const* d_in, const int* in_sizes, int n_in,
                              void* d_out, int out_size, void* d_ws, size_t ws_size,
                              hipStream_t stream) {
  const float* x    = (const float*)d_in[0];
  const float* lW   = (const float*)d_in[1];
  const float* lb   = (const float*)d_in[2];
  const float* rW   = (const float*)d_in[3];
  const float* rb   = (const float*)d_in[4];
  const float* lpad = (const float*)d_in[5];
  const float* rpad = (const float*)d_in[6];
  const float* lw   = (const float*)d_in[7];
  const float* rw   = (const float*)d_in[8];
  const float* lhwW = (const float*)d_in[9];
  const float* lhwb = (const float*)d_in[10];
  const float* rhwW = (const float*)d_in[11];
  const float* rhwb = (const float*)d_in[12];
  float* out = (float*)d_out;
  unsigned short* ws = (unsigned short*)d_ws;

  const size_t NIN  = (size_t)B_ * S2_ * D_;       // 4,259,840
  const size_t NQKV = (size_t)B_ * S2_ * 3072;     // 25,559,040
  const size_t MS   = (size_t)B_ * S_ * D_;        // 4,194,304
  const size_t DD   = (size_t)D_ * D_;             // 262,144
  const size_t LHW  = (size_t)1024 * 512;          // 524,288

  unsigned short* nin   = ws;
  unsigned short* qkv   = nin + NIN;
  unsigned short* ctx   = qkv + NQKV;              // (2,B,S,D)
  unsigned short* hwx   = ctx + 2 * MS;            // (2,B,S,D)
  unsigned short* hwy   = hwx + 2 * MS;            // (2,B,S,D)
  unsigned short* WTall = hwy + 2 * MS;            // (3072,512)
  unsigned short* WTp   = WTall + 6 * DD;          // (2,512,512)
  unsigned short* hWT   = WTp + 2 * DD;            // (2,2,1024,512)
  float* qkvbias        = (float*)(hWT + 4 * LHW); // 3072 fp32

  // --- prep ---
  k_prep<<<6188, 256, 0, stream>>>(x, lpad, rpad, lW, rW, lb, rb, lhwW, rhwW,
                                   WTall, WTp, hWT, nin, qkvbias);

  const int MQ = B_ * S2_;   // 8320

  // --- fused QKV both sides: (8320 x 3072), 128^2 2-phase + XCD swizzle ---
  {
    dim3 g(3072 / 128, MQ / 128, 1);   // (24, 65) -> 1560 blocks, %8==0
    k_gemm_mfma<<<g, 256, 0, stream>>>(nin, WTall, qkvbias, qkv, MQ, 3072, D_);
  }

  // --- mega cooperative kernel: attn + proj+rel + hw x2 ---
  {
    const unsigned short* a_qkv = qkv;
    unsigned short* a_ctx = ctx;
    const unsigned short* a_WTp = WTp;
    const unsigned short* a_nin = nin;
    const float* a_lb3 = lb + 3 * D_;
    const float* a_rb3 = rb + 3 * D_;
    const float* a_lw = lw;
    const float* a_rw = rw;
    unsigned short* a_hwx = hwx;
    unsigned short* a_hwy = hwy;
    const unsigned short* a_hWT = hWT;
    const float* a_lhwb = lhwb;
    const float* a_rhwb = rhwb;
    float* a_out = out;
    void* args[] = {&a_qkv, &a_ctx, &a_WTp, &a_nin, &a_lb3, &a_rb3,
                    &a_lw, &a_rw, &a_hwx, &a_hwy, &a_hWT, &a_lhwb,
                    &a_rhwb, &a_out};
    hipLaunchCooperativeKernel((void*)k_mega, dim3(256), dim3(512),
                               args, 0, stream);
  }
}

// Round 6
// 572.258 us; speedup vs baseline: 1.0017x; 1.0017x over previous
//
#include <hip/hip_runtime.h>
#include <hip/hip_cooperative_groups.h>
namespace cg = cooperative_groups;

// SelfAttentiveLBLBiLM on MI355X — round 13.
// r12 post-mortem: mega kernel spilled ~180 VGPRs/thread. launch_bounds
// (512,2) capped allocator at 128 VGPRs (512/4); attn phase needs ~150.
// Evidence: WRITE_SIZE 176MB vs 82MB expected -> 94MB excess / 131072 thr
// = 717 B/thread = 179 regs spill/restore. LDS (128KB) already forces
// 1 block/CU, so the (,2) hint bought nothing. Fix: (512,1) -> 256 VGPR
// budget, both attn (~150) and hw 8-phase (~190) fit. Nothing else changed.
// Dispatches: prep, qkv gemm(128^2+XCD swz), mega(attn|proj|hw x2).

#define B_ 8
#define S_ 1024
#define D_ 512
#define H_ 8
#define DK_ 64
#define WIDTH_ 8
#define S2_ 1040
#define NHW_ 2

typedef short bf16x8 __attribute__((ext_vector_type(8)));
typedef float f32x4 __attribute__((ext_vector_type(4)));

__device__ __forceinline__ float us2f(unsigned short u) {
  union { unsigned int i; float f; } c; c.i = ((unsigned int)u) << 16; return c.f;
}
__device__ __forceinline__ unsigned short f2us(float f) {
  union { float f; unsigned int i; } c; c.f = f;
  unsigned int x = c.i;
  return (unsigned short)((x + 0x7fffu + ((x >> 16) & 1u)) >> 16);
}
__device__ __forceinline__ unsigned int pack2(float a, float b) {
  return (unsigned int)f2us(a) | ((unsigned int)f2us(b) << 16);
}
__device__ __forceinline__ void async16(const void* g, void* l) {
  __builtin_amdgcn_global_load_lds(
      (const __attribute__((address_space(1))) void*)g,
      (__attribute__((address_space(3))) void*)l, 16, 0, 0);
}
__device__ __forceinline__ void unpack8(uint4 u, float* f) {
  unsigned int w[4] = {u.x, u.y, u.z, u.w};
  #pragma unroll
  for (int c = 0; c < 4; ++c) {
    union { unsigned int i; float g; } lo, hi;
    lo.i = w[c] << 16;
    hi.i = w[c] & 0xffff0000u;
    f[2 * c] = lo.g;
    f[2 * c + 1] = hi.g;
  }
}

// ---------------------------------------------------------------------------
// Prep mega-kernel (unchanged).
__global__ __launch_bounds__(256) void k_prep(
    const float* __restrict__ x,
    const float* __restrict__ lpad, const float* __restrict__ rpad,
    const float* __restrict__ lW, const float* __restrict__ rW,
    const float* __restrict__ lb, const float* __restrict__ rb,
    const float* __restrict__ lhwW, const float* __restrict__ rhwW,
    unsigned short* __restrict__ WTall, unsigned short* __restrict__ WTp,
    unsigned short* __restrict__ hWT,
    unsigned short* __restrict__ nin, float* __restrict__ qkvbias)
{
  __shared__ float tile[32][33];
  const size_t DD = (size_t)D_ * D_;
  int bx = blockIdx.x;
  int tx = threadIdx.x & 31, ty = threadIdx.x >> 5;

  if (bx < 2048) {                     // ---- attn transpose
    int sl = bx >> 8, rem = bx & 255;
    int side = sl >> 2, slice = sl & 3;
    int c0 = (rem & 15) * 32, r0 = (rem >> 4) * 32;
    const float* src = (side ? rW : lW) + (size_t)slice * DD;
    unsigned short* dst = (slice < 3) ? WTall + (size_t)(side * 3 + slice) * DD
                                      : WTp + (size_t)side * DD;
    #pragma unroll
    for (int i = 0; i < 4; ++i)
      tile[ty + i * 8][tx] = src[(size_t)(r0 + ty + i * 8) * D_ + c0 + tx];
    __syncthreads();
    #pragma unroll
    for (int i = 0; i < 4; ++i)
      dst[(size_t)(c0 + ty + i * 8) * D_ + r0 + tx] = f2us(tile[tx][ty + i * 8]);
    return;
  }
  if (bx < 4096) {                     // ---- hw transpose + interleave
    int idx = bx - 2048;
    int sl = idx >> 9, rem = idx & 511;    // sl: side*2+layer
    int c0 = (rem & 31) * 32, r0 = (rem >> 5) * 32;
    const float* src = ((sl >> 1) ? rhwW : lhwW) + (size_t)(sl & 1) * 512 * 1024;
    unsigned short* dst = hWT + (size_t)sl * 1024 * 512;
    #pragma unroll
    for (int i = 0; i < 4; ++i)
      tile[ty + i * 8][tx] = src[(size_t)(r0 + ty + i * 8) * 1024 + c0 + tx];
    __syncthreads();
    #pragma unroll
    for (int i = 0; i < 4; ++i) {
      int c = c0 + ty + i * 8;
      int cm = c & 511;
      int j = cm >> 4;
      int jl = j & 7;
      int Bq = ((jl >> 2) << 3) + (jl & 3) + ((c >= 512) ? 4 : 0);
      int q = (j >> 3) * 256 + Bq * 16 + (cm & 15);
      dst[(size_t)q * 512 + r0 + tx] = f2us(tile[tx][ty + i * 8]);
    }
    return;
  }
  // ---- build new_in + bias tail
  int gid = (bx - 4096) * 256 + threadIdx.x;
  const int NTH = B_ * S2_ * 64;       // 532,480
  if (gid >= NTH) {
    int t = gid - NTH;
    if (t < 1536) qkvbias[t] = lb[t];
    else if (t < 3072) qkvbias[t] = rb[t - 1536];
    return;
  }
  int c8 = (gid & 63) << 3;
  int row = gid >> 6;
  int b = row / S2_;
  int t = row - b * S2_;
  const float* src;
  if (t < WIDTH_)            src = lpad + (size_t)t * D_ + c8;
  else if (t >= S_ + WIDTH_) src = rpad + (size_t)(t - S_ - WIDTH_) * D_ + c8;
  else                       src = x + ((size_t)b * S_ + (t - WIDTH_)) * D_ + c8;
  float4 a = *reinterpret_cast<const float4*>(src);
  float4 c = *reinterpret_cast<const float4*>(src + 4);
  uint4 o;
  o.x = pack2(a.x, a.y); o.y = pack2(a.z, a.w);
  o.z = pack2(c.x, c.y); o.w = pack2(c.z, c.w);
  *reinterpret_cast<uint4*>(nin + (size_t)row * D_ + c8) = o;
}

// ---------------------------------------------------------------------------
// MFMA GEMM (QKV): 128^2 2-phase + XCD swizzle (unchanged).
__global__ __launch_bounds__(256) void k_gemm_mfma(
    const unsigned short* __restrict__ A,
    const unsigned short* __restrict__ BT,
    const float* __restrict__ bias,
    unsigned short* __restrict__ C,
    int M, int N, int K)
{
  __shared__ unsigned short As[128 * 64];
  __shared__ unsigned short Bs[128 * 64];

  const int tid = threadIdx.x;
  const int w = tid >> 6;
  const int l = tid & 63;

  const int gx = gridDim.x;
  const int nwg = gx * gridDim.y;
  const int flat = blockIdx.y * gx + blockIdx.x;
  const int cpx = nwg >> 3;
  const int nf = (flat & 7) * cpx + (flat >> 3);
  const int bm = (nf / gx) * 128;
  const int bn = (nf % gx) * 128;

  const int wrow = (w >> 1) * 64;
  const int wcol = (w & 1) * 64;

  const int lr = l >> 3;
  const int sk = (((l & 7) ^ lr) & 7) * 8;
  const unsigned short* Ap = A + (size_t)(bm + w * 8 + lr) * K + sk;
  const unsigned short* Bp = BT + (size_t)(bn + w * 8 + lr) * K + sk;
  unsigned short* lA = &As[w * 512];
  unsigned short* lB = &Bs[w * 512];
  const size_t K32 = (size_t)32 * K;

  const int fl = l & 15;
  const int fq = l >> 4;
  const int fx = fl & 7;

  f32x4 acc[4][4];
  #pragma unroll
  for (int mi = 0; mi < 4; ++mi)
    #pragma unroll
    for (int ni = 0; ni < 4; ++ni) acc[mi][ni] = (f32x4){0.f, 0.f, 0.f, 0.f};

  for (int k0 = 0; k0 < K; k0 += 64) {
    #pragma unroll
    for (int r = 0; r < 4; ++r) {
      async16(Ap + k0 + r * K32, lA + r * 2048);
      async16(Bp + k0 + r * K32, lB + r * 2048);
    }
    __syncthreads();
    #pragma unroll
    for (int s = 0; s < 2; ++s) {
      bf16x8 af[4], bfr[4];
      #pragma unroll
      for (int mi = 0; mi < 4; ++mi)
        af[mi] = *reinterpret_cast<const bf16x8*>(
            &As[(wrow + mi * 16 + fl) * 64 + (((s * 4 + fq) ^ fx) * 8)]);
      #pragma unroll
      for (int ni = 0; ni < 4; ++ni)
        bfr[ni] = *reinterpret_cast<const bf16x8*>(
            &Bs[(wcol + ni * 16 + fl) * 64 + (((s * 4 + fq) ^ fx) * 8)]);
      #pragma unroll
      for (int mi = 0; mi < 4; ++mi)
        #pragma unroll
        for (int ni = 0; ni < 4; ++ni)
          acc[mi][ni] = __builtin_amdgcn_mfma_f32_16x16x32_bf16(
              af[mi], bfr[ni], acc[mi][ni], 0, 0, 0);
    }
    __syncthreads();
  }

  float bv[4];
  #pragma unroll
  for (int ni = 0; ni < 4; ++ni) bv[ni] = bias[bn + wcol + ni * 16 + fl];

  const int rbase = (l >> 4) * 4;
  #pragma unroll
  for (int mi = 0; mi < 4; ++mi) {
    #pragma unroll
    for (int r = 0; r < 4; ++r) {
      int row = bm + wrow + mi * 16 + rbase + r;
      unsigned short* Cp = C + (size_t)row * N + bn + wcol + fl;
      #pragma unroll
      for (int ni = 0; ni < 4; ++ni)
        Cp[ni * 16] = f2us(acc[mi][ni][r] + bv[ni]);
    }
  }
}

// ---------------------------------------------------------------------------
// hw layer body: 256^2 8-phase GEMM + gate epilogue (proven r9-r11).
__device__ __forceinline__ void hw_layer(
    unsigned short* smem,
    const unsigned short* __restrict__ A,
    const unsigned short* __restrict__ BT,
    const float* __restrict__ bias,
    unsigned short* __restrict__ Obf,
    float* __restrict__ Ofp,
    int bx, int by, bool final_)
{
  const int tid = threadIdx.x;
  const int w = tid >> 6, l = tid & 63;
  const int wm = w >> 2, wn = w & 3;
  const int fl = l & 15, fq = l >> 4;
  const int bm = by * 256, bn = bx * 256;

  const int xorb = (fl & 7) << 4;
  const int cs0 = ((fq * 16) ^ xorb) >> 1;
  const int cs1 = ((64 + fq * 16) ^ xorb) >> 1;

  const int rr = l >> 3;
  const int ce = (((l & 7) * 16) ^ (rr << 4)) >> 1;
  const unsigned short* gA[2][2];
  const unsigned short* gB[2][2];
  #pragma unroll
  for (int i = 0; i < 2; ++i)
    #pragma unroll
    for (int h = 0; h < 2; ++h) {
      int ra = bm + h * 128 + (2 * w + i) * 8 + rr;
      gA[i][h] = A + (size_t)ra * 512 + ce;
      int rb = bn + h * 128 + (2 * w + i) * 8 + rr;
      gB[i][h] = BT + (size_t)rb * 512 + ce;
    }

  f32x4 acc[8][4];
  #pragma unroll
  for (int mi = 0; mi < 8; ++mi)
    #pragma unroll
    for (int ni = 0; ni < 4; ++ni) acc[mi][ni] = (f32x4){0.f, 0.f, 0.f, 0.f};

  bf16x8 ar[4][2], br[2][2];

#define BAR() __builtin_amdgcn_s_barrier()
#define STGA(buf, h, kt) do { \
    async16(gA[0][h] + (kt) * 64, &smem[((buf) * 2 + (h)) * 8192 + (2 * w) * 512]); \
    async16(gA[1][h] + (kt) * 64, &smem[((buf) * 2 + (h)) * 8192 + (2 * w + 1) * 512]); } while (0)
#define STGB(buf, h, kt) do { \
    async16(gB[0][h] + (kt) * 64, &smem[32768 + ((buf) * 2 + (h)) * 8192 + (2 * w) * 512]); \
    async16(gB[1][h] + (kt) * 64, &smem[32768 + ((buf) * 2 + (h)) * 8192 + (2 * w + 1) * 512]); } while (0)
#define LDA(buf, h) do { const unsigned short* p_ = &smem[((buf) * 2 + (h)) * 8192]; \
    _Pragma("unroll") for (int m4 = 0; m4 < 4; ++m4) { \
      int ro_ = ((2 * m4 + wm) * 16 + fl) * 64; \
      ar[m4][0] = *reinterpret_cast<const bf16x8*>(p_ + ro_ + cs0); \
      ar[m4][1] = *reinterpret_cast<const bf16x8*>(p_ + ro_ + cs1); } } while (0)
#define LDB(buf, h) do { const unsigned short* p_ = &smem[32768 + ((buf) * 2 + (h)) * 8192]; \
    _Pragma("unroll") for (int n2 = 0; n2 < 2; ++n2) { \
      int ro_ = ((4 * n2 + wn) * 16 + fl) * 64; \
      br[n2][0] = *reinterpret_cast<const bf16x8*>(p_ + ro_ + cs0); \
      br[n2][1] = *reinterpret_cast<const bf16x8*>(p_ + ro_ + cs1); } } while (0)
#define QUAD(miH, niH) do { __builtin_amdgcn_s_setprio(1); \
    _Pragma("unroll") for (int m4 = 0; m4 < 4; ++m4) \
      _Pragma("unroll") for (int n2 = 0; n2 < 2; ++n2) \
        _Pragma("unroll") for (int s_ = 0; s_ < 2; ++s_) \
          acc[(miH) * 4 + m4][(niH) * 2 + n2] = __builtin_amdgcn_mfma_f32_16x16x32_bf16( \
              ar[m4][s_], br[n2][s_], acc[(miH) * 4 + m4][(niH) * 2 + n2], 0, 0, 0); \
    __builtin_amdgcn_s_setprio(0); } while (0)

  STGA(0, 0, 0); STGB(0, 0, 0); STGB(0, 1, 0); STGA(0, 1, 0);
  STGA(1, 0, 1); STGB(1, 1, 1); STGA(1, 1, 1);
  asm volatile("s_waitcnt vmcnt(6)" ::: "memory");
  BAR();

  #pragma unroll 1
  for (int it = 0; it < 4; ++it) {
    const int t1 = 2 * it + 1, t2 = 2 * it + 2, t3 = 2 * it + 3;
    LDA(0, 0); LDB(0, 0);
    STGB(1, 0, t1);
    BAR(); QUAD(0, 0); BAR();
    LDB(0, 1);
    if (t2 < 8) STGA(0, 0, t2);
    BAR(); QUAD(0, 1); BAR();
    LDA(0, 1);
    if (t2 < 8) STGB(0, 1, t2);
    BAR(); QUAD(1, 1); BAR();
    LDB(0, 0);
    if (t2 < 8) STGA(0, 1, t2);
    BAR(); QUAD(1, 0);
    if (it < 3) asm volatile("s_waitcnt vmcnt(6)" ::: "memory");
    else        asm volatile("s_waitcnt vmcnt(0)" ::: "memory");
    BAR();
    LDA(1, 0); LDB(1, 0);
    if (t2 < 8) STGB(0, 0, t2);
    BAR(); QUAD(0, 0); BAR();
    LDB(1, 1);
    if (t3 < 8) STGA(1, 0, t3);
    BAR(); QUAD(0, 1); BAR();
    LDA(1, 1);
    if (t3 < 8) STGB(1, 1, t3);
    BAR(); QUAD(1, 1); BAR();
    LDB(1, 0);
    if (t3 < 8) STGA(1, 1, t3);
    BAR(); QUAD(1, 0);
    asm volatile("s_waitcnt vmcnt(6)" ::: "memory");
    BAR();
  }
#undef BAR
#undef STGA
#undef STGB
#undef LDA
#undef LDB
#undef QUAD

  float bnl[2], bg[2]; int xs[2];
  #pragma unroll
  for (int np = 0; np < 2; ++np) {
    xs[np] = (bx * 8 + np * 4 + wn) * 16 + fl;
    bnl[np] = bias[xs[np]];
    bg[np]  = bias[512 + xs[np]];
  }
  #pragma unroll
  for (int mi = 0; mi < 8; ++mi) {
    #pragma unroll
    for (int r = 0; r < 4; ++r) {
      int gr = bm + (2 * mi + wm) * 16 + fq * 4 + r;
      #pragma unroll
      for (int np = 0; np < 2; ++np) {
        float nl = fmaxf(acc[mi][2 * np][r] + bnl[np], 0.f);
        float g  = 1.f / (1.f + __expf(-(acc[mi][2 * np + 1][r] + bg[np])));
        float xv = us2f(A[(size_t)gr * 512 + xs[np]]);
        float res = g * xv + (1.f - g) * nl;
        if (final_) Ofp[(size_t)gr * 1024 + xs[np]] = res;
        else        Obf[(size_t)gr * 512 + xs[np]] = f2us(res);
      }
    }
  }
}

// ---------------------------------------------------------------------------
// Mega cooperative kernel: attn -> proj+rel -> hw x2. 256 blocks x 512 thr,
// 128KB LDS (1 block/CU). launch_bounds (512,1): 256-VGPR budget, no spill.
__global__ __launch_bounds__(512, 1) void k_mega(
    const unsigned short* __restrict__ qkv,
    unsigned short* __restrict__ ctx,
    const unsigned short* __restrict__ WTp,
    const unsigned short* __restrict__ nin,
    const float* __restrict__ lb3, const float* __restrict__ rb3,
    const float* __restrict__ wrel0, const float* __restrict__ wrel1,
    unsigned short* __restrict__ hwx,
    unsigned short* __restrict__ hwy,
    const unsigned short* __restrict__ hWT,
    const float* __restrict__ lhwb, const float* __restrict__ rhwb,
    float* __restrict__ out)
{
  __shared__ __align__(16) unsigned short smem[65536];   // 128 KiB
  cg::grid_group grid = cg::this_grid();
  const size_t MS = (size_t)B_ * S_ * D_;
  const size_t LHW = (size_t)1024 * 512;

  // ================= Phase A: windowed attention =================
  {
    const int lane = threadIdx.x & 63;
    const int wv = blockIdx.x * 8 + (threadIdx.x >> 6);   // 0..2047
    const int c0 = lane * 8;
    const int sg = wv & 255;
    const int b = (wv >> 8) & 7;
    const int s0 = sg << 2;
    const int i0 = s0 + WIDTH_;

    #pragma unroll 1
    for (int dir = 0; dir < 2; ++dir) {
      const size_t base = (size_t)b * S2_ * 3072 + dir * 1536;

      float qf[4][8];
      #pragma unroll
      for (int r = 0; r < 4; ++r)
        unpack8(*reinterpret_cast<const uint4*>(
            qkv + base + (size_t)(i0 + r) * 3072 + c0), qf[r]);

      float sc[4][10];
      float mx[4] = {-1e30f, -1e30f, -1e30f, -1e30f};
      #pragma unroll
      for (int t = 0; t < 13; ++t) {
        int j = (dir == 0) ? (i0 - 9 + t) : (i0 + t);
        bool ok = (j >= 0 && j < S2_);
        float kf[8];
        if (ok)
          unpack8(*reinterpret_cast<const uint4*>(
              qkv + base + (size_t)j * 3072 + 512 + c0), kf);
        #pragma unroll
        for (int r = 0; r < 4; ++r) {
          if (t < r || t > r + 9) continue;
          float sv = -1e30f;
          if (ok) {
            float p = qf[r][0] * kf[0];
            #pragma unroll
            for (int e = 1; e < 8; ++e) p += qf[r][e] * kf[e];
            p += __shfl_xor(p, 1);
            p += __shfl_xor(p, 2);
            p += __shfl_xor(p, 4);
            sv = p * 0.125f;
          }
          sc[r][t - r] = sv;
          mx[r] = fmaxf(mx[r], sv);
        }
      }

      float inv[4];
      #pragma unroll
      for (int r = 0; r < 4; ++r) {
        float den = 0.f;
        #pragma unroll
        for (int u = 0; u < 10; ++u) {
          sc[r][u] = (sc[r][u] > -1e29f) ? __expf(sc[r][u] - mx[r]) : 0.f;
          den += sc[r][u];
        }
        inv[r] = 1.f / den;
      }

      float acc[4][8];
      #pragma unroll
      for (int r = 0; r < 4; ++r)
        #pragma unroll
        for (int e = 0; e < 8; ++e) acc[r][e] = 0.f;

      #pragma unroll
      for (int t = 0; t < 13; ++t) {
        int j = (dir == 0) ? (i0 - 9 + t) : (i0 + t);
        bool ok = (j >= 0 && j < S2_);
        float vf[8];
        if (ok)
          unpack8(*reinterpret_cast<const uint4*>(
              qkv + base + (size_t)j * 3072 + 1024 + c0), vf);
        #pragma unroll
        for (int r = 0; r < 4; ++r) {
          if (t < r || t > r + 9) continue;
          if (ok) {
            float p = sc[r][t - r];
            #pragma unroll
            for (int e = 0; e < 8; ++e) acc[r][e] += p * vf[e];
          }
        }
      }

      #pragma unroll
      for (int r = 0; r < 4; ++r) {
        uint4 o;
        o.x = pack2(acc[r][0] * inv[r], acc[r][1] * inv[r]);
        o.y = pack2(acc[r][2] * inv[r], acc[r][3] * inv[r]);
        o.z = pack2(acc[r][4] * inv[r], acc[r][5] * inv[r]);
        o.w = pack2(acc[r][6] * inv[r], acc[r][7] * inv[r]);
        *reinterpret_cast<uint4*>(
            ctx + (((size_t)dir * B_ + b) * S_ + s0 + r) * D_ + c0) = o;
      }
    }
  }
  __threadfence();
  grid.sync();

  // ================= Phase P: proj + fused rel-add =================
  // Two virtual 128^2 blocks per physical block: waves 0-3 (h=0), 4-7 (h=1).
  // Identical barrier schedules; disjoint 34.8KB LDS halves.
  {
    const int h = threadIdx.x >> 8;
    const int t2 = threadIdx.x & 255;
    const int v = blockIdx.x * 2 + h;            // 0..511
    const int bx = v & 3, by = (v >> 2) & 63, z = v >> 8;
    unsigned short* sm = smem + h * 17408;       // 128*136 shorts per half
    unsigned short* As = sm;
    unsigned short* Bs = sm + 8192;
    const int K = 512;
    const unsigned short* A = ctx + (size_t)z * MS;
    const unsigned short* BT = WTp + (size_t)z * 262144;
    const float* bias = z ? rb3 : lb3;
    const float* wrel = z ? wrel1 : wrel0;
    const int off = z * WIDTH_;

    const int w = t2 >> 6;
    const int l = t2 & 63;
    const int bm = by * 128;
    const int bn = bx * 128;
    const int wrow = (w >> 1) * 64;
    const int wcol = (w & 1) * 64;

    const int lr = l >> 3;
    const int sk = (((l & 7) ^ lr) & 7) * 8;
    const unsigned short* Ap = A + (size_t)(bm + w * 8 + lr) * K + sk;
    const unsigned short* Bp = BT + (size_t)(bn + w * 8 + lr) * K + sk;
    unsigned short* lA = &As[w * 512];
    unsigned short* lB = &Bs[w * 512];
    const size_t K32 = (size_t)32 * K;

    const int fl = t2 & 15;
    const int fq = l >> 4;
    const int fx = fl & 7;

    f32x4 acc[4][4];
    #pragma unroll
    for (int mi = 0; mi < 4; ++mi)
      #pragma unroll
      for (int ni = 0; ni < 4; ++ni) acc[mi][ni] = (f32x4){0.f, 0.f, 0.f, 0.f};

    for (int k0 = 0; k0 < K; k0 += 64) {
      #pragma unroll
      for (int r = 0; r < 4; ++r) {
        async16(Ap + k0 + r * K32, lA + r * 2048);
        async16(Bp + k0 + r * K32, lB + r * 2048);
      }
      __syncthreads();
      #pragma unroll
      for (int s = 0; s < 2; ++s) {
        bf16x8 af[4], bfr[4];
        #pragma unroll
        for (int mi = 0; mi < 4; ++mi)
          af[mi] = *reinterpret_cast<const bf16x8*>(
              &As[(wrow + mi * 16 + fl) * 64 + (((s * 4 + fq) ^ fx) * 8)]);
        #pragma unroll
        for (int ni = 0; ni < 4; ++ni)
          bfr[ni] = *reinterpret_cast<const bf16x8*>(
              &Bs[(wcol + ni * 16 + fl) * 64 + (((s * 4 + fq) ^ fx) * 8)]);
        #pragma unroll
        for (int mi = 0; mi < 4; ++mi)
          #pragma unroll
          for (int ni = 0; ni < 4; ++ni)
            acc[mi][ni] = __builtin_amdgcn_mfma_f32_16x16x32_bf16(
                af[mi], bfr[ni], acc[mi][ni], 0, 0, 0);
      }
      __syncthreads();
    }

    float bv[4];
    #pragma unroll
    for (int ni = 0; ni < 4; ++ni) bv[ni] = bias[bn + wcol + ni * 16 + fl];
    const int rbase = (l >> 4) * 4;
    #pragma unroll
    for (int mi = 0; mi < 4; ++mi)
      #pragma unroll
      for (int r = 0; r < 4; ++r)
        #pragma unroll
        for (int ni = 0; ni < 4; ++ni)
          sm[(wrow + mi * 16 + rbase + r) * 136 + wcol + ni * 16 + fl] =
              f2us(acc[mi][ni][r] + bv[ni]);
    __syncthreads();

    const int trow = t2 >> 4;
    const int tcol = (t2 & 15) * 8;
    const float wj[9] = {wrel[0], wrel[1], wrel[2], wrel[3], wrel[4],
                         wrel[5], wrel[6], wrel[7], wrel[8]};
    #pragma unroll
    for (int i = 0; i < 8; ++i) {
      int r = trow + i * 16;
      int gr = bm + r;
      int b = gr >> 10, s = gr & (S_ - 1);
      float a8[8];
      unpack8(*reinterpret_cast<const uint4*>(&sm[r * 136 + tcol]), a8);
      const unsigned short* np =
          nin + ((size_t)b * S2_ + off + s) * D_ + bn + tcol;
      #pragma unroll
      for (int j = 0; j < 9; ++j) {
        float nf[8];
        unpack8(*reinterpret_cast<const uint4*>(np + (size_t)j * D_), nf);
        #pragma unroll
        for (int e = 0; e < 8; ++e) a8[e] += wj[j] * nf[e];
      }
      uint4 o;
      o.x = pack2(a8[0], a8[1]); o.y = pack2(a8[2], a8[3]);
      o.z = pack2(a8[4], a8[5]); o.w = pack2(a8[6], a8[7]);
      *reinterpret_cast<uint4*>(
          hwx + (size_t)z * MS + (size_t)gr * D_ + bn + tcol) = o;
    }
  }
  __threadfence();
  grid.sync();

  // ================= Phase H: highway layers x2 =================
  {
    const int bx = blockIdx.x & 3;
    const int by = (blockIdx.x >> 2) & 31;
    const int z = blockIdx.x >> 7;
    #pragma unroll 1
    for (int lay = 0; lay < 2; ++lay) {
      const unsigned short* A  = (lay ? hwy : hwx) + (size_t)z * MS;
      const unsigned short* BT = hWT + ((size_t)(z * 2 + lay)) * LHW;
      const float* bias = (z ? rhwb : lhwb) + lay * 1024;
      hw_layer(smem, A, BT, bias,
               hwy + (size_t)z * MS,
               out + (size_t)z * 512,
               bx, by, lay == 1);
      if (lay == 0) { __threadfence(); grid.sync(); }
    }
  }
}

// ---------------------------------------------------------------------------
extern "C" void kernel_launch(void* const* d_in, const int* in_sizes, int n_in,
                              void* d_out, int out_size, void* d_ws, size_t ws_size,
                              hipStream_t stream) {
  const float* x    = (const float*)d_in[0];
  const float* lW   = (const float*)d_in[1];
  const float* lb   = (const float*)d_in[2];
  const float* rW   = (const float*)d_in[3];
  const float* rb   = (const float*)d_in[4];
  const float* lpad = (const float*)d_in[5];
  const float* rpad = (const float*)d_in[6];
  const float* lw   = (const float*)d_in[7];
  const float* rw   = (const float*)d_in[8];
  const float* lhwW = (const float*)d_in[9];
  const float* lhwb = (const float*)d_in[10];
  const float* rhwW = (const float*)d_in[11];
  const float* rhwb = (const float*)d_in[12];
  float* out = (float*)d_out;
  unsigned short* ws = (unsigned short*)d_ws;

  const size_t NIN  = (size_t)B_ * S2_ * D_;       // 4,259,840
  const size_t NQKV = (size_t)B_ * S2_ * 3072;     // 25,559,040
  const size_t MS   = (size_t)B_ * S_ * D_;        // 4,194,304
  const size_t DD   = (size_t)D_ * D_;             // 262,144
  const size_t LHW  = (size_t)1024 * 512;          // 524,288

  unsigned short* nin   = ws;
  unsigned short* qkv   = nin + NIN;
  unsigned short* ctx   = qkv + NQKV;              // (2,B,S,D)
  unsigned short* hwx   = ctx + 2 * MS;            // (2,B,S,D)
  unsigned short* hwy   = hwx + 2 * MS;            // (2,B,S,D)
  unsigned short* WTall = hwy + 2 * MS;            // (3072,512)
  unsigned short* WTp   = WTall + 6 * DD;          // (2,512,512)
  unsigned short* hWT   = WTp + 2 * DD;            // (2,2,1024,512)
  float* qkvbias        = (float*)(hWT + 4 * LHW); // 3072 fp32

  // --- prep ---
  k_prep<<<6188, 256, 0, stream>>>(x, lpad, rpad, lW, rW, lb, rb, lhwW, rhwW,
                                   WTall, WTp, hWT, nin, qkvbias);

  const int MQ = B_ * S2_;   // 8320

  // --- fused QKV both sides: (8320 x 3072), 128^2 2-phase + XCD swizzle ---
  {
    dim3 g(3072 / 128, MQ / 128, 1);   // (24, 65) -> 1560 blocks, %8==0
    k_gemm_mfma<<<g, 256, 0, stream>>>(nin, WTall, qkvbias, qkv, MQ, 3072, D_);
  }

  // --- mega cooperative kernel: attn + proj+rel + hw x2 ---
  {
    const unsigned short* a_qkv = qkv;
    unsigned short* a_ctx = ctx;
    const unsigned short* a_WTp = WTp;
    const unsigned short* a_nin = nin;
    const float* a_lb3 = lb + 3 * D_;
    const float* a_rb3 = rb + 3 * D_;
    const float* a_lw = lw;
    const float* a_rw = rw;
    unsigned short* a_hwx = hwx;
    unsigned short* a_hwy = hwy;
    const unsigned short* a_hWT = hWT;
    const float* a_lhwb = lhwb;
    const float* a_rhwb = rhwb;
    float* a_out = out;
    void* args[] = {&a_qkv, &a_ctx, &a_WTp, &a_nin, &a_lb3, &a_rb3,
                    &a_lw, &a_rw, &a_hwx, &a_hwy, &a_hWT, &a_lhwb,
                    &a_rhwb, &a_out};
    hipLaunchCooperativeKernel((void*)k_mega, dim3(256), dim3(512),
                               args, 0, stream);
  }
}

// Round 7
// 235.646 us; speedup vs baseline: 2.4325x; 2.4285x over previous
//
#include <hip/hip_runtime.h>

// SelfAttentiveLBLBiLM on MI355X — round 14.
// r12/r13 post-mortem: mega-fusion dead end (VGPR stuck at 128, ~180 reg
// scratch spill, 418us). REVERTED to r11 structure (best: 235.4us).
// Key accounting from r12/r13: residual (total - visible kernels) ~110us at
// BOTH 6 launches (r11) and 3 launches (r13) -> gaps are small; the hidden
// ~90-110us is k_prep (roofline only ~25-30us) or harness reset. This round
// splits prep into prep_w (transposes) / prep_x (new_in+bias) with identical
// bodies for visibility: a pathological half (>43.8us) will surface in top-5.
// Dispatches: prep_w, prep_x, qkv(128^2+XCD swz), attn(4-row),
// proj+rel(128^2), hw 256^2 8-phase x2.

#define B_ 8
#define S_ 1024
#define D_ 512
#define H_ 8
#define DK_ 64
#define WIDTH_ 8
#define S2_ 1040
#define NHW_ 2

typedef short bf16x8 __attribute__((ext_vector_type(8)));
typedef float f32x4 __attribute__((ext_vector_type(4)));

__device__ __forceinline__ float us2f(unsigned short u) {
  union { unsigned int i; float f; } c; c.i = ((unsigned int)u) << 16; return c.f;
}
__device__ __forceinline__ unsigned short f2us(float f) {
  union { float f; unsigned int i; } c; c.f = f;
  unsigned int x = c.i;
  return (unsigned short)((x + 0x7fffu + ((x >> 16) & 1u)) >> 16);
}
__device__ __forceinline__ unsigned int pack2(float a, float b) {
  return (unsigned int)f2us(a) | ((unsigned int)f2us(b) << 16);
}
__device__ __forceinline__ void async16(const void* g, void* l) {
  __builtin_amdgcn_global_load_lds(
      (const __attribute__((address_space(1))) void*)g,
      (__attribute__((address_space(3))) void*)l, 16, 0, 0);
}
__device__ __forceinline__ void unpack8(uint4 u, float* f) {
  unsigned int w[4] = {u.x, u.y, u.z, u.w};
  #pragma unroll
  for (int c = 0; c < 4; ++c) {
    union { unsigned int i; float g; } lo, hi;
    lo.i = w[c] << 16;
    hi.i = w[c] & 0xffff0000u;
    f[2 * c] = lo.g;
    f[2 * c + 1] = hi.g;
  }
}

// ---------------------------------------------------------------------------
// Prep (weights): [0,2048) attn W transpose; [2048,4096) hw W transpose.
__global__ __launch_bounds__(256) void k_prep_w(
    const float* __restrict__ lW, const float* __restrict__ rW,
    const float* __restrict__ lhwW, const float* __restrict__ rhwW,
    unsigned short* __restrict__ WTall, unsigned short* __restrict__ WTp,
    unsigned short* __restrict__ hWT)
{
  __shared__ float tile[32][33];
  const size_t DD = (size_t)D_ * D_;
  int bx = blockIdx.x;
  int tx = threadIdx.x & 31, ty = threadIdx.x >> 5;

  if (bx < 2048) {                     // ---- attn transpose
    int sl = bx >> 8, rem = bx & 255;
    int side = sl >> 2, slice = sl & 3;
    int c0 = (rem & 15) * 32, r0 = (rem >> 4) * 32;
    const float* src = (side ? rW : lW) + (size_t)slice * DD;
    unsigned short* dst = (slice < 3) ? WTall + (size_t)(side * 3 + slice) * DD
                                      : WTp + (size_t)side * DD;
    #pragma unroll
    for (int i = 0; i < 4; ++i)
      tile[ty + i * 8][tx] = src[(size_t)(r0 + ty + i * 8) * D_ + c0 + tx];
    __syncthreads();
    #pragma unroll
    for (int i = 0; i < 4; ++i)
      dst[(size_t)(c0 + ty + i * 8) * D_ + r0 + tx] = f2us(tile[tx][ty + i * 8]);
    return;
  }
  // ---- hw transpose + interleave (256-tile pairing)
  int idx = bx - 2048;
  int sl = idx >> 9, rem = idx & 511;    // sl: side*2+layer
  int c0 = (rem & 31) * 32, r0 = (rem >> 5) * 32;
  const float* src = ((sl >> 1) ? rhwW : lhwW) + (size_t)(sl & 1) * 512 * 1024;
  unsigned short* dst = hWT + (size_t)sl * 1024 * 512;
  #pragma unroll
  for (int i = 0; i < 4; ++i)
    tile[ty + i * 8][tx] = src[(size_t)(r0 + ty + i * 8) * 1024 + c0 + tx];
  __syncthreads();
  #pragma unroll
  for (int i = 0; i < 4; ++i) {
    int c = c0 + ty + i * 8;
    int cm = c & 511;
    int j = cm >> 4;                       // 16-col block of x, 0..31
    int jl = j & 7;
    int Bq = ((jl >> 2) << 3) + (jl & 3) + ((c >= 512) ? 4 : 0);
    int q = (j >> 3) * 256 + Bq * 16 + (cm & 15);
    dst[(size_t)q * 512 + r0 + tx] = f2us(tile[tx][ty + i * 8]);
  }
}

// ---------------------------------------------------------------------------
// Prep (activations): build new_in + qkv bias tail.
__global__ __launch_bounds__(256) void k_prep_x(
    const float* __restrict__ x,
    const float* __restrict__ lpad, const float* __restrict__ rpad,
    const float* __restrict__ lb, const float* __restrict__ rb,
    unsigned short* __restrict__ nin, float* __restrict__ qkvbias)
{
  int gid = blockIdx.x * 256 + threadIdx.x;
  const int NTH = B_ * S2_ * 64;       // 532,480
  if (gid >= NTH) {
    int t = gid - NTH;
    if (t < 1536) qkvbias[t] = lb[t];
    else if (t < 3072) qkvbias[t] = rb[t - 1536];
    return;
  }
  int c8 = (gid & 63) << 3;
  int row = gid >> 6;
  int b = row / S2_;
  int t = row - b * S2_;
  const float* src;
  if (t < WIDTH_)            src = lpad + (size_t)t * D_ + c8;
  else if (t >= S_ + WIDTH_) src = rpad + (size_t)(t - S_ - WIDTH_) * D_ + c8;
  else                       src = x + ((size_t)b * S_ + (t - WIDTH_)) * D_ + c8;
  float4 a = *reinterpret_cast<const float4*>(src);
  float4 c = *reinterpret_cast<const float4*>(src + 4);
  uint4 o;
  o.x = pack2(a.x, a.y); o.y = pack2(a.z, a.w);
  o.z = pack2(c.x, c.y); o.w = pack2(c.z, c.w);
  *reinterpret_cast<uint4*>(nin + (size_t)row * D_ + c8) = o;
}

// ---------------------------------------------------------------------------
// MFMA GEMM (QKV): C(M,N) = A(M,K) @ BT(N,K)^T + bias(N).
// BK=64, XOR-swizzled LDS, tile 128x128, 4 waves, XCD-swizzled grid.
__global__ __launch_bounds__(256) void k_gemm_mfma(
    const unsigned short* __restrict__ A,
    const unsigned short* __restrict__ BT,
    const float* __restrict__ bias,
    unsigned short* __restrict__ C,
    int M, int N, int K)
{
  __shared__ unsigned short As[128 * 64];
  __shared__ unsigned short Bs[128 * 64];

  const int tid = threadIdx.x;
  const int w = tid >> 6;
  const int l = tid & 63;

  // bijective XCD swizzle (nwg % 8 == 0)
  const int gx = gridDim.x;
  const int nwg = gx * gridDim.y;
  const int flat = blockIdx.y * gx + blockIdx.x;
  const int cpx = nwg >> 3;
  const int nf = (flat & 7) * cpx + (flat >> 3);
  const int bm = (nf / gx) * 128;
  const int bn = (nf % gx) * 128;

  const int wrow = (w >> 1) * 64;
  const int wcol = (w & 1) * 64;

  const int lr = l >> 3;
  const int sk = (((l & 7) ^ lr) & 7) * 8;
  const unsigned short* Ap = A + (size_t)(bm + w * 8 + lr) * K + sk;
  const unsigned short* Bp = BT + (size_t)(bn + w * 8 + lr) * K + sk;
  unsigned short* lA = &As[w * 512];
  unsigned short* lB = &Bs[w * 512];
  const size_t K32 = (size_t)32 * K;

  const int fl = l & 15;
  const int fq = l >> 4;
  const int fx = fl & 7;

  f32x4 acc[4][4];
  #pragma unroll
  for (int mi = 0; mi < 4; ++mi)
    #pragma unroll
    for (int ni = 0; ni < 4; ++ni) acc[mi][ni] = (f32x4){0.f, 0.f, 0.f, 0.f};

  for (int k0 = 0; k0 < K; k0 += 64) {
    #pragma unroll
    for (int r = 0; r < 4; ++r) {
      async16(Ap + k0 + r * K32, lA + r * 2048);
      async16(Bp + k0 + r * K32, lB + r * 2048);
    }
    __syncthreads();
    #pragma unroll
    for (int s = 0; s < 2; ++s) {
      bf16x8 af[4], bfr[4];
      #pragma unroll
      for (int mi = 0; mi < 4; ++mi)
        af[mi] = *reinterpret_cast<const bf16x8*>(
            &As[(wrow + mi * 16 + fl) * 64 + (((s * 4 + fq) ^ fx) * 8)]);
      #pragma unroll
      for (int ni = 0; ni < 4; ++ni)
        bfr[ni] = *reinterpret_cast<const bf16x8*>(
            &Bs[(wcol + ni * 16 + fl) * 64 + (((s * 4 + fq) ^ fx) * 8)]);
      #pragma unroll
      for (int mi = 0; mi < 4; ++mi)
        #pragma unroll
        for (int ni = 0; ni < 4; ++ni)
          acc[mi][ni] = __builtin_amdgcn_mfma_f32_16x16x32_bf16(
              af[mi], bfr[ni], acc[mi][ni], 0, 0, 0);
    }
    __syncthreads();
  }

  float bv[4];
  #pragma unroll
  for (int ni = 0; ni < 4; ++ni) bv[ni] = bias[bn + wcol + ni * 16 + fl];

  const int rbase = (l >> 4) * 4;
  #pragma unroll
  for (int mi = 0; mi < 4; ++mi) {
    #pragma unroll
    for (int r = 0; r < 4; ++r) {
      int row = bm + wrow + mi * 16 + rbase + r;
      unsigned short* Cp = C + (size_t)row * N + bn + wcol + fl;
      #pragma unroll
      for (int ni = 0; ni < 4; ++ni)
        Cp[ni * 16] = f2us(acc[mi][ni][r] + bv[ni]);
    }
  }
}

// ---------------------------------------------------------------------------
// 256x256 8-phase GEMM, K=512 (hw layers only: grid exactly 256 blocks).
//  EPI=1: highway gate -> bf16 (z*MS + row*512 + x)
//  EPI=2: highway gate -> f32  (row*1024 + z*512 + x)
template <int EPI>
__global__ __launch_bounds__(512, 2) void k_gemm256(
    const unsigned short* __restrict__ Abase, size_t aStrZ,
    const unsigned short* __restrict__ BTbase, size_t bStrZ,
    const float* __restrict__ bias0, const float* __restrict__ bias1,
    unsigned short* __restrict__ Cbf, float* __restrict__ Cfp,
    int M, int N)
{
  __shared__ __align__(16) unsigned short smem[65536];   // 128 KiB
  const int tid = threadIdx.x;
  const int w = tid >> 6, l = tid & 63;
  const int wm = w >> 2, wn = w & 3;
  const int fl = l & 15, fq = l >> 4;
  const int z = blockIdx.z;
  const unsigned short* A = Abase + (size_t)z * aStrZ;
  const unsigned short* BT = BTbase + (size_t)z * bStrZ;
  const int bm = blockIdx.y * 256, bn = blockIdx.x * 256;

  const int xorb = (fl & 7) << 4;
  const int cs0 = ((fq * 16) ^ xorb) >> 1;        // k-slice 0
  const int cs1 = ((64 + fq * 16) ^ xorb) >> 1;   // k-slice 1

  const int rr = l >> 3;
  const int ce = (((l & 7) * 16) ^ (rr << 4)) >> 1;   // shorts
  const unsigned short* gA[2][2];
  const unsigned short* gB[2][2];
  #pragma unroll
  for (int i = 0; i < 2; ++i)
    #pragma unroll
    for (int h = 0; h < 2; ++h) {
      int ra = bm + h * 128 + (2 * w + i) * 8 + rr;
      if (ra > M - 1) ra = M - 1;
      gA[i][h] = A + (size_t)ra * 512 + ce;
      int rb = bn + h * 128 + (2 * w + i) * 8 + rr;
      gB[i][h] = BT + (size_t)rb * 512 + ce;
    }

  f32x4 acc[8][4];
  #pragma unroll
  for (int mi = 0; mi < 8; ++mi)
    #pragma unroll
    for (int ni = 0; ni < 4; ++ni) acc[mi][ni] = (f32x4){0.f, 0.f, 0.f, 0.f};

  bf16x8 ar[4][2], br[2][2];

#define BAR() __builtin_amdgcn_s_barrier()
#define STGA(buf, h, kt) do { \
    async16(gA[0][h] + (kt) * 64, &smem[((buf) * 2 + (h)) * 8192 + (2 * w) * 512]); \
    async16(gA[1][h] + (kt) * 64, &smem[((buf) * 2 + (h)) * 8192 + (2 * w + 1) * 512]); } while (0)
#define STGB(buf, h, kt) do { \
    async16(gB[0][h] + (kt) * 64, &smem[32768 + ((buf) * 2 + (h)) * 8192 + (2 * w) * 512]); \
    async16(gB[1][h] + (kt) * 64, &smem[32768 + ((buf) * 2 + (h)) * 8192 + (2 * w + 1) * 512]); } while (0)
#define LDA(buf, h) do { const unsigned short* p_ = &smem[((buf) * 2 + (h)) * 8192]; \
    _Pragma("unroll") for (int m4 = 0; m4 < 4; ++m4) { \
      int ro_ = ((2 * m4 + wm) * 16 + fl) * 64; \
      ar[m4][0] = *reinterpret_cast<const bf16x8*>(p_ + ro_ + cs0); \
      ar[m4][1] = *reinterpret_cast<const bf16x8*>(p_ + ro_ + cs1); } } while (0)
#define LDB(buf, h) do { const unsigned short* p_ = &smem[32768 + ((buf) * 2 + (h)) * 8192]; \
    _Pragma("unroll") for (int n2 = 0; n2 < 2; ++n2) { \
      int ro_ = ((4 * n2 + wn) * 16 + fl) * 64; \
      br[n2][0] = *reinterpret_cast<const bf16x8*>(p_ + ro_ + cs0); \
      br[n2][1] = *reinterpret_cast<const bf16x8*>(p_ + ro_ + cs1); } } while (0)
#define QUAD(miH, niH) do { __builtin_amdgcn_s_setprio(1); \
    _Pragma("unroll") for (int m4 = 0; m4 < 4; ++m4) \
      _Pragma("unroll") for (int n2 = 0; n2 < 2; ++n2) \
        _Pragma("unroll") for (int s_ = 0; s_ < 2; ++s_) \
          acc[(miH) * 4 + m4][(niH) * 2 + n2] = __builtin_amdgcn_mfma_f32_16x16x32_bf16( \
              ar[m4][s_], br[n2][s_], acc[(miH) * 4 + m4][(niH) * 2 + n2], 0, 0, 0); \
    __builtin_amdgcn_s_setprio(0); } while (0)

  // prologue: T0 {A0,B0,B1,A1} -> buf0, T1 {A0,B1,A1} -> buf1 (B0 at I1).
  STGA(0, 0, 0); STGB(0, 0, 0); STGB(0, 1, 0); STGA(0, 1, 0);
  STGA(1, 0, 1); STGB(1, 1, 1); STGA(1, 1, 1);
  asm volatile("s_waitcnt vmcnt(6)" ::: "memory");   // T0 fully landed
  BAR();

  #pragma unroll 1
  for (int it = 0; it < 4; ++it) {
    const int t1 = 2 * it + 1, t2 = 2 * it + 2, t3 = 2 * it + 3;
    LDA(0, 0); LDB(0, 0);
    STGB(1, 0, t1);
    BAR(); QUAD(0, 0); BAR();
    LDB(0, 1);
    if (t2 < 8) STGA(0, 0, t2);
    BAR(); QUAD(0, 1); BAR();
    LDA(0, 1);
    if (t2 < 8) STGB(0, 1, t2);
    BAR(); QUAD(1, 1); BAR();
    LDB(0, 0);
    if (t2 < 8) STGA(0, 1, t2);
    BAR(); QUAD(1, 0);
    if (it < 3) asm volatile("s_waitcnt vmcnt(6)" ::: "memory");
    else        asm volatile("s_waitcnt vmcnt(0)" ::: "memory");
    BAR();
    LDA(1, 0); LDB(1, 0);
    if (t2 < 8) STGB(0, 0, t2);
    BAR(); QUAD(0, 0); BAR();
    LDB(1, 1);
    if (t3 < 8) STGA(1, 0, t3);
    BAR(); QUAD(0, 1); BAR();
    LDA(1, 1);
    if (t3 < 8) STGB(1, 1, t3);
    BAR(); QUAD(1, 1); BAR();
    LDB(1, 0);
    if (t3 < 8) STGA(1, 1, t3);
    BAR(); QUAD(1, 0);
    asm volatile("s_waitcnt vmcnt(6)" ::: "memory");
    BAR();
  }
#undef BAR
#undef STGA
#undef STGB
#undef LDA
#undef LDB
#undef QUAD

  // ---- epilogue (hw gate)
  {
    const float* bias = z ? bias1 : bias0;
    const size_t MS = (size_t)B_ * S_ * D_;
    float bnl[2], bg[2]; int xs[2];
    #pragma unroll
    for (int np = 0; np < 2; ++np) {
      xs[np] = (blockIdx.x * 8 + np * 4 + wn) * 16 + fl;
      bnl[np] = bias[xs[np]];
      bg[np]  = bias[512 + xs[np]];
    }
    #pragma unroll
    for (int mi = 0; mi < 8; ++mi) {
      #pragma unroll
      for (int r = 0; r < 4; ++r) {
        int gr = bm + (2 * mi + wm) * 16 + fq * 4 + r;
        #pragma unroll
        for (int np = 0; np < 2; ++np) {
          float nl = fmaxf(acc[mi][2 * np][r] + bnl[np], 0.f);
          float g  = 1.f / (1.f + __expf(-(acc[mi][2 * np + 1][r] + bg[np])));
          float xv = us2f(A[(size_t)gr * 512 + xs[np]]);
          float res = g * xv + (1.f - g) * nl;
          if (EPI == 2) Cfp[(size_t)gr * 1024 + (size_t)z * 512 + xs[np]] = res;
          else Cbf[(size_t)z * MS + (size_t)gr * 512 + xs[np]] = f2us(res);
        }
      }
    }
  }
}

// ---------------------------------------------------------------------------
// Proj GEMM + fused rel-add (128^2 structure). A = ctx (2,8192,512) bf16.
__global__ __launch_bounds__(256) void k_gemm_proj(
    const unsigned short* __restrict__ ctx,
    const unsigned short* __restrict__ WTp,    // (2,512,512)
    const unsigned short* __restrict__ nin,    // (B,S2,512)
    const float* __restrict__ lb3, const float* __restrict__ rb3,
    const float* __restrict__ wrel0, const float* __restrict__ wrel1,
    unsigned short* __restrict__ hwx)          // (2,8192,512)
{
  __shared__ unsigned short smem[128 * 136];   // 34.8 KB; staging uses 32 KB
  unsigned short* As = smem;
  unsigned short* Bs = smem + 8192;
  const int K = 512, N = 512;
  const size_t MS = (size_t)B_ * S_ * D_;

  const int z = blockIdx.z;
  const unsigned short* A = ctx + (size_t)z * MS;
  const unsigned short* BT = WTp + (size_t)z * 512 * 512;
  const float* bias = z ? rb3 : lb3;
  const float* wrel = z ? wrel1 : wrel0;
  const int off = z * WIDTH_;

  const int tid = threadIdx.x;
  const int w = tid >> 6;
  const int l = tid & 63;
  const int bm = blockIdx.y * 128;
  const int bn = blockIdx.x * 128;
  const int wrow = (w >> 1) * 64;
  const int wcol = (w & 1) * 64;

  const int lr = l >> 3;
  const int sk = (((l & 7) ^ lr) & 7) * 8;
  const unsigned short* Ap = A + (size_t)(bm + w * 8 + lr) * K + sk;
  const unsigned short* Bp = BT + (size_t)(bn + w * 8 + lr) * K + sk;
  unsigned short* lA = &As[w * 512];
  unsigned short* lB = &Bs[w * 512];
  const size_t K32 = (size_t)32 * K;

  const int fl = l & 15;
  const int fq = l >> 4;
  const int fx = fl & 7;

  f32x4 acc[4][4];
  #pragma unroll
  for (int mi = 0; mi < 4; ++mi)
    #pragma unroll
    for (int ni = 0; ni < 4; ++ni) acc[mi][ni] = (f32x4){0.f, 0.f, 0.f, 0.f};

  for (int k0 = 0; k0 < K; k0 += 64) {
    #pragma unroll
    for (int r = 0; r < 4; ++r) {
      async16(Ap + k0 + r * K32, lA + r * 2048);
      async16(Bp + k0 + r * K32, lB + r * 2048);
    }
    __syncthreads();
    #pragma unroll
    for (int s = 0; s < 2; ++s) {
      bf16x8 af[4], bfr[4];
      #pragma unroll
      for (int mi = 0; mi < 4; ++mi)
        af[mi] = *reinterpret_cast<const bf16x8*>(
            &As[(wrow + mi * 16 + fl) * 64 + (((s * 4 + fq) ^ fx) * 8)]);
      #pragma unroll
      for (int ni = 0; ni < 4; ++ni)
        bfr[ni] = *reinterpret_cast<const bf16x8*>(
            &Bs[(wcol + ni * 16 + fl) * 64 + (((s * 4 + fq) ^ fx) * 8)]);
      #pragma unroll
      for (int mi = 0; mi < 4; ++mi)
        #pragma unroll
        for (int ni = 0; ni < 4; ++ni)
          acc[mi][ni] = __builtin_amdgcn_mfma_f32_16x16x32_bf16(
              af[mi], bfr[ni], acc[mi][ni], 0, 0, 0);
    }
    __syncthreads();
  }

  // stage bias-added tile into LDS (bf16, ld 136)
  float bv[4];
  #pragma unroll
  for (int ni = 0; ni < 4; ++ni) bv[ni] = bias[bn + wcol + ni * 16 + fl];
  const int rbase = (l >> 4) * 4;
  #pragma unroll
  for (int mi = 0; mi < 4; ++mi)
    #pragma unroll
    for (int r = 0; r < 4; ++r)
      #pragma unroll
      for (int ni = 0; ni < 4; ++ni)
        smem[(wrow + mi * 16 + rbase + r) * 136 + wcol + ni * 16 + fl] =
            f2us(acc[mi][ni][r] + bv[ni]);
  __syncthreads();

  // cooperative rel-add: 16 threads per tile row, 8-col chunks
  const int trow = tid >> 4;
  const int tcol = (tid & 15) * 8;
  const float wj[9] = {wrel[0], wrel[1], wrel[2], wrel[3], wrel[4],
                       wrel[5], wrel[6], wrel[7], wrel[8]};
  #pragma unroll
  for (int i = 0; i < 8; ++i) {
    int r = trow + i * 16;
    int gr = bm + r;
    int b = gr >> 10, s = gr & (S_ - 1);
    float a8[8];
    unpack8(*reinterpret_cast<const uint4*>(&smem[r * 136 + tcol]), a8);
    const unsigned short* np =
        nin + ((size_t)b * S2_ + off + s) * D_ + bn + tcol;
    #pragma unroll
    for (int j = 0; j < 9; ++j) {
      float nf[8];
      unpack8(*reinterpret_cast<const uint4*>(np + (size_t)j * D_), nf);
      #pragma unroll
      for (int e = 0; e < 8; ++e) a8[e] += wj[j] * nf[e];
    }
    uint4 o;
    o.x = pack2(a8[0], a8[1]); o.y = pack2(a8[2], a8[3]);
    o.z = pack2(a8[4], a8[5]); o.w = pack2(a8[6], a8[7]);
    *reinterpret_cast<uint4*>(
        hwx + (size_t)z * MS + (size_t)gr * D_ + bn + tcol) = o;
  }
}

// ---------------------------------------------------------------------------
// Windowed attention, 4 consecutive rows per wave sharing a 13-row K/V
// window (r11-proven).
__global__ __launch_bounds__(256) void k_attn_window(
    const unsigned short* __restrict__ qkv,
    unsigned short* __restrict__ ctx)
{
  int wid = (blockIdx.x * 256 + threadIdx.x) >> 6;   // dir*2048 + b*256 + sg
  int lane = threadIdx.x & 63;
  int sg = wid & 255;
  int b = (wid >> 8) & 7;
  int dir = wid >> 11;
  int s0 = sg << 2;
  int i0 = s0 + WIDTH_;

  const size_t base = (size_t)b * S2_ * 3072 + dir * 1536;
  const int c0 = lane * 8;

  float qf[4][8];
  #pragma unroll
  for (int r = 0; r < 4; ++r)
    unpack8(*reinterpret_cast<const uint4*>(
        qkv + base + (size_t)(i0 + r) * 3072 + c0), qf[r]);

  float sc[4][10];
  float mx[4] = {-1e30f, -1e30f, -1e30f, -1e30f};
  #pragma unroll
  for (int t = 0; t < 13; ++t) {
    int j = (dir == 0) ? (i0 - 9 + t) : (i0 + t);
    bool ok = (j >= 0 && j < S2_);           // wave-uniform
    float kf[8];
    if (ok)
      unpack8(*reinterpret_cast<const uint4*>(
          qkv + base + (size_t)j * 3072 + 512 + c0), kf);
    #pragma unroll
    for (int r = 0; r < 4; ++r) {
      if (t < r || t > r + 9) continue;      // compile-time prune
      float sv = -1e30f;
      if (ok) {
        float p = qf[r][0] * kf[0];
        #pragma unroll
        for (int e = 1; e < 8; ++e) p += qf[r][e] * kf[e];
        p += __shfl_xor(p, 1);
        p += __shfl_xor(p, 2);
        p += __shfl_xor(p, 4);
        sv = p * 0.125f;
      }
      sc[r][t - r] = sv;
      mx[r] = fmaxf(mx[r], sv);
    }
  }

  float inv[4];
  #pragma unroll
  for (int r = 0; r < 4; ++r) {
    float den = 0.f;
    #pragma unroll
    for (int u = 0; u < 10; ++u) {
      sc[r][u] = (sc[r][u] > -1e29f) ? __expf(sc[r][u] - mx[r]) : 0.f;
      den += sc[r][u];
    }
    inv[r] = 1.f / den;
  }

  float acc[4][8];
  #pragma unroll
  for (int r = 0; r < 4; ++r)
    #pragma unroll
    for (int e = 0; e < 8; ++e) acc[r][e] = 0.f;

  #pragma unroll
  for (int t = 0; t < 13; ++t) {
    int j = (dir == 0) ? (i0 - 9 + t) : (i0 + t);
    bool ok = (j >= 0 && j < S2_);
    float vf[8];
    if (ok)
      unpack8(*reinterpret_cast<const uint4*>(
          qkv + base + (size_t)j * 3072 + 1024 + c0), vf);
    #pragma unroll
    for (int r = 0; r < 4; ++r) {
      if (t < r || t > r + 9) continue;
      if (ok) {
        float p = sc[r][t - r];
        #pragma unroll
        for (int e = 0; e < 8; ++e) acc[r][e] += p * vf[e];
      }
    }
  }

  #pragma unroll
  for (int r = 0; r < 4; ++r) {
    uint4 o;
    o.x = pack2(acc[r][0] * inv[r], acc[r][1] * inv[r]);
    o.y = pack2(acc[r][2] * inv[r], acc[r][3] * inv[r]);
    o.z = pack2(acc[r][4] * inv[r], acc[r][5] * inv[r]);
    o.w = pack2(acc[r][6] * inv[r], acc[r][7] * inv[r]);
    *reinterpret_cast<uint4*>(
        ctx + (((size_t)dir * B_ + b) * S_ + s0 + r) * D_ + c0) = o;
  }
}

// ---------------------------------------------------------------------------
extern "C" void kernel_launch(void* const* d_in, const int* in_sizes, int n_in,
                              void* d_out, int out_size, void* d_ws, size_t ws_size,
                              hipStream_t stream) {
  const float* x    = (const float*)d_in[0];
  const float* lW   = (const float*)d_in[1];
  const float* lb   = (const float*)d_in[2];
  const float* rW   = (const float*)d_in[3];
  const float* rb   = (const float*)d_in[4];
  const float* lpad = (const float*)d_in[5];
  const float* rpad = (const float*)d_in[6];
  const float* lw   = (const float*)d_in[7];
  const float* rw   = (const float*)d_in[8];
  const float* lhwW = (const float*)d_in[9];
  const float* lhwb = (const float*)d_in[10];
  const float* rhwW = (const float*)d_in[11];
  const float* rhwb = (const float*)d_in[12];
  float* out = (float*)d_out;
  unsigned short* ws = (unsigned short*)d_ws;

  const size_t NIN  = (size_t)B_ * S2_ * D_;       // 4,259,840
  const size_t NQKV = (size_t)B_ * S2_ * 3072;     // 25,559,040
  const size_t MS   = (size_t)B_ * S_ * D_;        // 4,194,304
  const size_t DD   = (size_t)D_ * D_;             // 262,144
  const size_t LHW  = (size_t)1024 * 512;          // 524,288

  unsigned short* nin   = ws;
  unsigned short* qkv   = nin + NIN;
  unsigned short* ctx   = qkv + NQKV;              // (2,B,S,D)
  unsigned short* hwx   = ctx + 2 * MS;            // (2,B,S,D)
  unsigned short* hwy   = hwx + 2 * MS;            // (2,B,S,D)
  unsigned short* WTall = hwy + 2 * MS;            // (3072,512)
  unsigned short* WTp   = WTall + 6 * DD;          // (2,512,512)
  unsigned short* hWT   = WTp + 2 * DD;            // (2,2,1024,512)
  float* qkvbias        = (float*)(hWT + 4 * LHW); // 3072 fp32

  // --- prep: 2 dispatches (split for per-kernel visibility) ---
  k_prep_w<<<4096, 256, 0, stream>>>(lW, rW, lhwW, rhwW, WTall, WTp, hWT);
  k_prep_x<<<2092, 256, 0, stream>>>(x, lpad, rpad, lb, rb, nin, qkvbias);

  const int MQ = B_ * S2_;   // 8320

  // --- fused QKV both sides: (8320 x 3072), 128^2 2-phase + XCD swizzle ---
  {
    dim3 g(3072 / 128, MQ / 128, 1);   // (24, 65) -> 1560 blocks, %8==0
    k_gemm_mfma<<<g, 256, 0, stream>>>(nin, WTall, qkvbias, qkv, MQ, 3072, D_);
  }

  // --- attention, both sides, 4 rows/wave ---
  k_attn_window<<<(2 * B_ * S_) / 16, 256, 0, stream>>>(qkv, ctx);

  // --- proj + fused rel-add, z-batched over side (128^2 kernel) ---
  {
    dim3 g(D_ / 128, (B_ * S_) / 128, 2);   // (4, 64, 2)
    k_gemm_proj<<<g, 256, 0, stream>>>(ctx, WTp, nin, lb + 3 * D_, rb + 3 * D_,
                                       lw, rw, hwx);
  }

  // --- highway layers: 256^2 8-phase + fused gate, z-batched over side ---
  {
    dim3 g(1024 / 256, (B_ * S_) / 256, 2);   // (4, 32, 2)
    k_gemm256<1><<<g, 512, 0, stream>>>(hwx, MS, hWT, 2 * LHW,
                                        lhwb, rhwb, hwy, nullptr,
                                        B_ * S_, 1024);
    k_gemm256<2><<<g, 512, 0, stream>>>(hwy, MS, hWT + LHW, 2 * LHW,
                                        lhwb + 1024, rhwb + 1024,
                                        nullptr, out, B_ * S_, 1024);
  }
}

// Round 8
// 232.605 us; speedup vs baseline: 2.4643x; 1.0131x over previous
//
#include <hip/hip_runtime.h>

// SelfAttentiveLBLBiLM on MI355X — round 15.
// r14 post-mortem: r11 parity restored (235.6); +1 launch = +0.2us -> launch
// gaps ~0.2us each, NOT the residual. No prep half in top-5 -> all non-QKV
// kernels < 44us; their sum ~190us (each just under cutoff + harness reset).
// QKV closed by arithmetic: 597 TF = structure's short-K ceiling (912 x 8/9.75
// x tail); 256^2-8ph measured worse (49.7); 128x256 EV~0 (m105 -10% offsets
// prologue gain). This round: proj rel-add sliding window — thread handles 8
// CONSECUTIVE rows (2 half-groups of 4), exploiting 8/9 window overlap:
// 72 -> 24 uint4 loads + unpacks per thread, FMA count and per-output
// summation order identical (bitwise-same result).
// Dispatches: prep_w, prep_x, qkv(128^2+XCD swz), attn(4-row),
// proj+rel(128^2, sliding), hw 256^2 8-phase x2.

#define B_ 8
#define S_ 1024
#define D_ 512
#define H_ 8
#define DK_ 64
#define WIDTH_ 8
#define S2_ 1040
#define NHW_ 2

typedef short bf16x8 __attribute__((ext_vector_type(8)));
typedef float f32x4 __attribute__((ext_vector_type(4)));

__device__ __forceinline__ float us2f(unsigned short u) {
  union { unsigned int i; float f; } c; c.i = ((unsigned int)u) << 16; return c.f;
}
__device__ __forceinline__ unsigned short f2us(float f) {
  union { float f; unsigned int i; } c; c.f = f;
  unsigned int x = c.i;
  return (unsigned short)((x + 0x7fffu + ((x >> 16) & 1u)) >> 16);
}
__device__ __forceinline__ unsigned int pack2(float a, float b) {
  return (unsigned int)f2us(a) | ((unsigned int)f2us(b) << 16);
}
__device__ __forceinline__ void async16(const void* g, void* l) {
  __builtin_amdgcn_global_load_lds(
      (const __attribute__((address_space(1))) void*)g,
      (__attribute__((address_space(3))) void*)l, 16, 0, 0);
}
__device__ __forceinline__ void unpack8(uint4 u, float* f) {
  unsigned int w[4] = {u.x, u.y, u.z, u.w};
  #pragma unroll
  for (int c = 0; c < 4; ++c) {
    union { unsigned int i; float g; } lo, hi;
    lo.i = w[c] << 16;
    hi.i = w[c] & 0xffff0000u;
    f[2 * c] = lo.g;
    f[2 * c + 1] = hi.g;
  }
}

// ---------------------------------------------------------------------------
// Prep (weights): [0,2048) attn W transpose; [2048,4096) hw W transpose.
__global__ __launch_bounds__(256) void k_prep_w(
    const float* __restrict__ lW, const float* __restrict__ rW,
    const float* __restrict__ lhwW, const float* __restrict__ rhwW,
    unsigned short* __restrict__ WTall, unsigned short* __restrict__ WTp,
    unsigned short* __restrict__ hWT)
{
  __shared__ float tile[32][33];
  const size_t DD = (size_t)D_ * D_;
  int bx = blockIdx.x;
  int tx = threadIdx.x & 31, ty = threadIdx.x >> 5;

  if (bx < 2048) {                     // ---- attn transpose
    int sl = bx >> 8, rem = bx & 255;
    int side = sl >> 2, slice = sl & 3;
    int c0 = (rem & 15) * 32, r0 = (rem >> 4) * 32;
    const float* src = (side ? rW : lW) + (size_t)slice * DD;
    unsigned short* dst = (slice < 3) ? WTall + (size_t)(side * 3 + slice) * DD
                                      : WTp + (size_t)side * DD;
    #pragma unroll
    for (int i = 0; i < 4; ++i)
      tile[ty + i * 8][tx] = src[(size_t)(r0 + ty + i * 8) * D_ + c0 + tx];
    __syncthreads();
    #pragma unroll
    for (int i = 0; i < 4; ++i)
      dst[(size_t)(c0 + ty + i * 8) * D_ + r0 + tx] = f2us(tile[tx][ty + i * 8]);
    return;
  }
  // ---- hw transpose + interleave (256-tile pairing)
  int idx = bx - 2048;
  int sl = idx >> 9, rem = idx & 511;    // sl: side*2+layer
  int c0 = (rem & 31) * 32, r0 = (rem >> 5) * 32;
  const float* src = ((sl >> 1) ? rhwW : lhwW) + (size_t)(sl & 1) * 512 * 1024;
  unsigned short* dst = hWT + (size_t)sl * 1024 * 512;
  #pragma unroll
  for (int i = 0; i < 4; ++i)
    tile[ty + i * 8][tx] = src[(size_t)(r0 + ty + i * 8) * 1024 + c0 + tx];
  __syncthreads();
  #pragma unroll
  for (int i = 0; i < 4; ++i) {
    int c = c0 + ty + i * 8;
    int cm = c & 511;
    int j = cm >> 4;                       // 16-col block of x, 0..31
    int jl = j & 7;
    int Bq = ((jl >> 2) << 3) + (jl & 3) + ((c >= 512) ? 4 : 0);
    int q = (j >> 3) * 256 + Bq * 16 + (cm & 15);
    dst[(size_t)q * 512 + r0 + tx] = f2us(tile[tx][ty + i * 8]);
  }
}

// ---------------------------------------------------------------------------
// Prep (activations): build new_in + qkv bias tail.
__global__ __launch_bounds__(256) void k_prep_x(
    const float* __restrict__ x,
    const float* __restrict__ lpad, const float* __restrict__ rpad,
    const float* __restrict__ lb, const float* __restrict__ rb,
    unsigned short* __restrict__ nin, float* __restrict__ qkvbias)
{
  int gid = blockIdx.x * 256 + threadIdx.x;
  const int NTH = B_ * S2_ * 64;       // 532,480
  if (gid >= NTH) {
    int t = gid - NTH;
    if (t < 1536) qkvbias[t] = lb[t];
    else if (t < 3072) qkvbias[t] = rb[t - 1536];
    return;
  }
  int c8 = (gid & 63) << 3;
  int row = gid >> 6;
  int b = row / S2_;
  int t = row - b * S2_;
  const float* src;
  if (t < WIDTH_)            src = lpad + (size_t)t * D_ + c8;
  else if (t >= S_ + WIDTH_) src = rpad + (size_t)(t - S_ - WIDTH_) * D_ + c8;
  else                       src = x + ((size_t)b * S_ + (t - WIDTH_)) * D_ + c8;
  float4 a = *reinterpret_cast<const float4*>(src);
  float4 c = *reinterpret_cast<const float4*>(src + 4);
  uint4 o;
  o.x = pack2(a.x, a.y); o.y = pack2(a.z, a.w);
  o.z = pack2(c.x, c.y); o.w = pack2(c.z, c.w);
  *reinterpret_cast<uint4*>(nin + (size_t)row * D_ + c8) = o;
}

// ---------------------------------------------------------------------------
// MFMA GEMM (QKV): C(M,N) = A(M,K) @ BT(N,K)^T + bias(N).
// BK=64, XOR-swizzled LDS, tile 128x128, 4 waves, XCD-swizzled grid.
__global__ __launch_bounds__(256) void k_gemm_mfma(
    const unsigned short* __restrict__ A,
    const unsigned short* __restrict__ BT,
    const float* __restrict__ bias,
    unsigned short* __restrict__ C,
    int M, int N, int K)
{
  __shared__ unsigned short As[128 * 64];
  __shared__ unsigned short Bs[128 * 64];

  const int tid = threadIdx.x;
  const int w = tid >> 6;
  const int l = tid & 63;

  // bijective XCD swizzle (nwg % 8 == 0)
  const int gx = gridDim.x;
  const int nwg = gx * gridDim.y;
  const int flat = blockIdx.y * gx + blockIdx.x;
  const int cpx = nwg >> 3;
  const int nf = (flat & 7) * cpx + (flat >> 3);
  const int bm = (nf / gx) * 128;
  const int bn = (nf % gx) * 128;

  const int wrow = (w >> 1) * 64;
  const int wcol = (w & 1) * 64;

  const int lr = l >> 3;
  const int sk = (((l & 7) ^ lr) & 7) * 8;
  const unsigned short* Ap = A + (size_t)(bm + w * 8 + lr) * K + sk;
  const unsigned short* Bp = BT + (size_t)(bn + w * 8 + lr) * K + sk;
  unsigned short* lA = &As[w * 512];
  unsigned short* lB = &Bs[w * 512];
  const size_t K32 = (size_t)32 * K;

  const int fl = l & 15;
  const int fq = l >> 4;
  const int fx = fl & 7;

  f32x4 acc[4][4];
  #pragma unroll
  for (int mi = 0; mi < 4; ++mi)
    #pragma unroll
    for (int ni = 0; ni < 4; ++ni) acc[mi][ni] = (f32x4){0.f, 0.f, 0.f, 0.f};

  for (int k0 = 0; k0 < K; k0 += 64) {
    #pragma unroll
    for (int r = 0; r < 4; ++r) {
      async16(Ap + k0 + r * K32, lA + r * 2048);
      async16(Bp + k0 + r * K32, lB + r * 2048);
    }
    __syncthreads();
    #pragma unroll
    for (int s = 0; s < 2; ++s) {
      bf16x8 af[4], bfr[4];
      #pragma unroll
      for (int mi = 0; mi < 4; ++mi)
        af[mi] = *reinterpret_cast<const bf16x8*>(
            &As[(wrow + mi * 16 + fl) * 64 + (((s * 4 + fq) ^ fx) * 8)]);
      #pragma unroll
      for (int ni = 0; ni < 4; ++ni)
        bfr[ni] = *reinterpret_cast<const bf16x8*>(
            &Bs[(wcol + ni * 16 + fl) * 64 + (((s * 4 + fq) ^ fx) * 8)]);
      #pragma unroll
      for (int mi = 0; mi < 4; ++mi)
        #pragma unroll
        for (int ni = 0; ni < 4; ++ni)
          acc[mi][ni] = __builtin_amdgcn_mfma_f32_16x16x32_bf16(
              af[mi], bfr[ni], acc[mi][ni], 0, 0, 0);
    }
    __syncthreads();
  }

  float bv[4];
  #pragma unroll
  for (int ni = 0; ni < 4; ++ni) bv[ni] = bias[bn + wcol + ni * 16 + fl];

  const int rbase = (l >> 4) * 4;
  #pragma unroll
  for (int mi = 0; mi < 4; ++mi) {
    #pragma unroll
    for (int r = 0; r < 4; ++r) {
      int row = bm + wrow + mi * 16 + rbase + r;
      unsigned short* Cp = C + (size_t)row * N + bn + wcol + fl;
      #pragma unroll
      for (int ni = 0; ni < 4; ++ni)
        Cp[ni * 16] = f2us(acc[mi][ni][r] + bv[ni]);
    }
  }
}

// ---------------------------------------------------------------------------
// 256x256 8-phase GEMM, K=512 (hw layers only: grid exactly 256 blocks).
//  EPI=1: highway gate -> bf16 (z*MS + row*512 + x)
//  EPI=2: highway gate -> f32  (row*1024 + z*512 + x)
template <int EPI>
__global__ __launch_bounds__(512, 2) void k_gemm256(
    const unsigned short* __restrict__ Abase, size_t aStrZ,
    const unsigned short* __restrict__ BTbase, size_t bStrZ,
    const float* __restrict__ bias0, const float* __restrict__ bias1,
    unsigned short* __restrict__ Cbf, float* __restrict__ Cfp,
    int M, int N)
{
  __shared__ __align__(16) unsigned short smem[65536];   // 128 KiB
  const int tid = threadIdx.x;
  const int w = tid >> 6, l = tid & 63;
  const int wm = w >> 2, wn = w & 3;
  const int fl = l & 15, fq = l >> 4;
  const int z = blockIdx.z;
  const unsigned short* A = Abase + (size_t)z * aStrZ;
  const unsigned short* BT = BTbase + (size_t)z * bStrZ;
  const int bm = blockIdx.y * 256, bn = blockIdx.x * 256;

  const int xorb = (fl & 7) << 4;
  const int cs0 = ((fq * 16) ^ xorb) >> 1;        // k-slice 0
  const int cs1 = ((64 + fq * 16) ^ xorb) >> 1;   // k-slice 1

  const int rr = l >> 3;
  const int ce = (((l & 7) * 16) ^ (rr << 4)) >> 1;   // shorts
  const unsigned short* gA[2][2];
  const unsigned short* gB[2][2];
  #pragma unroll
  for (int i = 0; i < 2; ++i)
    #pragma unroll
    for (int h = 0; h < 2; ++h) {
      int ra = bm + h * 128 + (2 * w + i) * 8 + rr;
      if (ra > M - 1) ra = M - 1;
      gA[i][h] = A + (size_t)ra * 512 + ce;
      int rb = bn + h * 128 + (2 * w + i) * 8 + rr;
      gB[i][h] = BT + (size_t)rb * 512 + ce;
    }

  f32x4 acc[8][4];
  #pragma unroll
  for (int mi = 0; mi < 8; ++mi)
    #pragma unroll
    for (int ni = 0; ni < 4; ++ni) acc[mi][ni] = (f32x4){0.f, 0.f, 0.f, 0.f};

  bf16x8 ar[4][2], br[2][2];

#define BAR() __builtin_amdgcn_s_barrier()
#define STGA(buf, h, kt) do { \
    async16(gA[0][h] + (kt) * 64, &smem[((buf) * 2 + (h)) * 8192 + (2 * w) * 512]); \
    async16(gA[1][h] + (kt) * 64, &smem[((buf) * 2 + (h)) * 8192 + (2 * w + 1) * 512]); } while (0)
#define STGB(buf, h, kt) do { \
    async16(gB[0][h] + (kt) * 64, &smem[32768 + ((buf) * 2 + (h)) * 8192 + (2 * w) * 512]); \
    async16(gB[1][h] + (kt) * 64, &smem[32768 + ((buf) * 2 + (h)) * 8192 + (2 * w + 1) * 512]); } while (0)
#define LDA(buf, h) do { const unsigned short* p_ = &smem[((buf) * 2 + (h)) * 8192]; \
    _Pragma("unroll") for (int m4 = 0; m4 < 4; ++m4) { \
      int ro_ = ((2 * m4 + wm) * 16 + fl) * 64; \
      ar[m4][0] = *reinterpret_cast<const bf16x8*>(p_ + ro_ + cs0); \
      ar[m4][1] = *reinterpret_cast<const bf16x8*>(p_ + ro_ + cs1); } } while (0)
#define LDB(buf, h) do { const unsigned short* p_ = &smem[32768 + ((buf) * 2 + (h)) * 8192]; \
    _Pragma("unroll") for (int n2 = 0; n2 < 2; ++n2) { \
      int ro_ = ((4 * n2 + wn) * 16 + fl) * 64; \
      br[n2][0] = *reinterpret_cast<const bf16x8*>(p_ + ro_ + cs0); \
      br[n2][1] = *reinterpret_cast<const bf16x8*>(p_ + ro_ + cs1); } } while (0)
#define QUAD(miH, niH) do { __builtin_amdgcn_s_setprio(1); \
    _Pragma("unroll") for (int m4 = 0; m4 < 4; ++m4) \
      _Pragma("unroll") for (int n2 = 0; n2 < 2; ++n2) \
        _Pragma("unroll") for (int s_ = 0; s_ < 2; ++s_) \
          acc[(miH) * 4 + m4][(niH) * 2 + n2] = __builtin_amdgcn_mfma_f32_16x16x32_bf16( \
              ar[m4][s_], br[n2][s_], acc[(miH) * 4 + m4][(niH) * 2 + n2], 0, 0, 0); \
    __builtin_amdgcn_s_setprio(0); } while (0)

  // prologue: T0 {A0,B0,B1,A1} -> buf0, T1 {A0,B1,A1} -> buf1 (B0 at I1).
  STGA(0, 0, 0); STGB(0, 0, 0); STGB(0, 1, 0); STGA(0, 1, 0);
  STGA(1, 0, 1); STGB(1, 1, 1); STGA(1, 1, 1);
  asm volatile("s_waitcnt vmcnt(6)" ::: "memory");   // T0 fully landed
  BAR();

  #pragma unroll 1
  for (int it = 0; it < 4; ++it) {
    const int t1 = 2 * it + 1, t2 = 2 * it + 2, t3 = 2 * it + 3;
    LDA(0, 0); LDB(0, 0);
    STGB(1, 0, t1);
    BAR(); QUAD(0, 0); BAR();
    LDB(0, 1);
    if (t2 < 8) STGA(0, 0, t2);
    BAR(); QUAD(0, 1); BAR();
    LDA(0, 1);
    if (t2 < 8) STGB(0, 1, t2);
    BAR(); QUAD(1, 1); BAR();
    LDB(0, 0);
    if (t2 < 8) STGA(0, 1, t2);
    BAR(); QUAD(1, 0);
    if (it < 3) asm volatile("s_waitcnt vmcnt(6)" ::: "memory");
    else        asm volatile("s_waitcnt vmcnt(0)" ::: "memory");
    BAR();
    LDA(1, 0); LDB(1, 0);
    if (t2 < 8) STGB(0, 0, t2);
    BAR(); QUAD(0, 0); BAR();
    LDB(1, 1);
    if (t3 < 8) STGA(1, 0, t3);
    BAR(); QUAD(0, 1); BAR();
    LDA(1, 1);
    if (t3 < 8) STGB(1, 1, t3);
    BAR(); QUAD(1, 1); BAR();
    LDB(1, 0);
    if (t3 < 8) STGA(1, 1, t3);
    BAR(); QUAD(1, 0);
    asm volatile("s_waitcnt vmcnt(6)" ::: "memory");
    BAR();
  }
#undef BAR
#undef STGA
#undef STGB
#undef LDA
#undef LDB
#undef QUAD

  // ---- epilogue (hw gate)
  {
    const float* bias = z ? bias1 : bias0;
    const size_t MS = (size_t)B_ * S_ * D_;
    float bnl[2], bg[2]; int xs[2];
    #pragma unroll
    for (int np = 0; np < 2; ++np) {
      xs[np] = (blockIdx.x * 8 + np * 4 + wn) * 16 + fl;
      bnl[np] = bias[xs[np]];
      bg[np]  = bias[512 + xs[np]];
    }
    #pragma unroll
    for (int mi = 0; mi < 8; ++mi) {
      #pragma unroll
      for (int r = 0; r < 4; ++r) {
        int gr = bm + (2 * mi + wm) * 16 + fq * 4 + r;
        #pragma unroll
        for (int np = 0; np < 2; ++np) {
          float nl = fmaxf(acc[mi][2 * np][r] + bnl[np], 0.f);
          float g  = 1.f / (1.f + __expf(-(acc[mi][2 * np + 1][r] + bg[np])));
          float xv = us2f(A[(size_t)gr * 512 + xs[np]]);
          float res = g * xv + (1.f - g) * nl;
          if (EPI == 2) Cfp[(size_t)gr * 1024 + (size_t)z * 512 + xs[np]] = res;
          else Cbf[(size_t)z * MS + (size_t)gr * 512 + xs[np]] = f2us(res);
        }
      }
    }
  }
}

// ---------------------------------------------------------------------------
// Proj GEMM + fused rel-add (128^2 structure). A = ctx (2,8192,512) bf16.
// r15: sliding-window rel-add — 8 consecutive rows/thread (2 half-groups of
// 4), 24 nin loads instead of 72; per-output summation order unchanged.
__global__ __launch_bounds__(256) void k_gemm_proj(
    const unsigned short* __restrict__ ctx,
    const unsigned short* __restrict__ WTp,    // (2,512,512)
    const unsigned short* __restrict__ nin,    // (B,S2,512)
    const float* __restrict__ lb3, const float* __restrict__ rb3,
    const float* __restrict__ wrel0, const float* __restrict__ wrel1,
    unsigned short* __restrict__ hwx)          // (2,8192,512)
{
  __shared__ unsigned short smem[128 * 136];   // 34.8 KB; staging uses 32 KB
  unsigned short* As = smem;
  unsigned short* Bs = smem + 8192;
  const int K = 512;
  const size_t MS = (size_t)B_ * S_ * D_;

  const int z = blockIdx.z;
  const unsigned short* A = ctx + (size_t)z * MS;
  const unsigned short* BT = WTp + (size_t)z * 512 * 512;
  const float* bias = z ? rb3 : lb3;
  const float* wrel = z ? wrel1 : wrel0;
  const int off = z * WIDTH_;

  const int tid = threadIdx.x;
  const int w = tid >> 6;
  const int l = tid & 63;
  const int bm = blockIdx.y * 128;
  const int bn = blockIdx.x * 128;
  const int wrow = (w >> 1) * 64;
  const int wcol = (w & 1) * 64;

  const int lr = l >> 3;
  const int sk = (((l & 7) ^ lr) & 7) * 8;
  const unsigned short* Ap = A + (size_t)(bm + w * 8 + lr) * K + sk;
  const unsigned short* Bp = BT + (size_t)(bn + w * 8 + lr) * K + sk;
  unsigned short* lA = &As[w * 512];
  unsigned short* lB = &Bs[w * 512];
  const size_t K32 = (size_t)32 * K;

  const int fl = l & 15;
  const int fq = l >> 4;
  const int fx = fl & 7;

  f32x4 acc[4][4];
  #pragma unroll
  for (int mi = 0; mi < 4; ++mi)
    #pragma unroll
    for (int ni = 0; ni < 4; ++ni) acc[mi][ni] = (f32x4){0.f, 0.f, 0.f, 0.f};

  for (int k0 = 0; k0 < K; k0 += 64) {
    #pragma unroll
    for (int r = 0; r < 4; ++r) {
      async16(Ap + k0 + r * K32, lA + r * 2048);
      async16(Bp + k0 + r * K32, lB + r * 2048);
    }
    __syncthreads();
    #pragma unroll
    for (int s = 0; s < 2; ++s) {
      bf16x8 af[4], bfr[4];
      #pragma unroll
      for (int mi = 0; mi < 4; ++mi)
        af[mi] = *reinterpret_cast<const bf16x8*>(
            &As[(wrow + mi * 16 + fl) * 64 + (((s * 4 + fq) ^ fx) * 8)]);
      #pragma unroll
      for (int ni = 0; ni < 4; ++ni)
        bfr[ni] = *reinterpret_cast<const bf16x8*>(
            &Bs[(wcol + ni * 16 + fl) * 64 + (((s * 4 + fq) ^ fx) * 8)]);
      #pragma unroll
      for (int mi = 0; mi < 4; ++mi)
        #pragma unroll
        for (int ni = 0; ni < 4; ++ni)
          acc[mi][ni] = __builtin_amdgcn_mfma_f32_16x16x32_bf16(
              af[mi], bfr[ni], acc[mi][ni], 0, 0, 0);
    }
    __syncthreads();
  }

  // stage bias-added tile into LDS (bf16, ld 136)
  float bv[4];
  #pragma unroll
  for (int ni = 0; ni < 4; ++ni) bv[ni] = bias[bn + wcol + ni * 16 + fl];
  const int rbase = (l >> 4) * 4;
  #pragma unroll
  for (int mi = 0; mi < 4; ++mi)
    #pragma unroll
    for (int r = 0; r < 4; ++r)
      #pragma unroll
      for (int ni = 0; ni < 4; ++ni)
        smem[(wrow + mi * 16 + rbase + r) * 136 + wcol + ni * 16 + fl] =
            f2us(acc[mi][ni][r] + bv[ni]);
  __syncthreads();

  // sliding-window rel-add: thread = (8-consecutive-row group, 8-col chunk).
  // Row a (0..7 in group) taps nin rows off+s0+a .. off+s0+a+8, weight
  // wj[t-a]. Group taps span 16 rows -> 2 half-groups x 12 loads = 24 loads.
  // Groups are 8-aligned so never straddle a batch boundary; max nin row
  // = off + 1016 + 15 <= 1039 < S2, always in-bounds.
  const float wj[9] = {wrel[0], wrel[1], wrel[2], wrel[3], wrel[4],
                       wrel[5], wrel[6], wrel[7], wrel[8]};
  const int g8 = (tid >> 4) * 8;
  const int tcol = (tid & 15) * 8;
  {
    int gr0 = bm + g8;
    int b0 = gr0 >> 10, s0 = gr0 & (S_ - 1);
    const unsigned short* np =
        nin + ((size_t)b0 * S2_ + off + s0) * D_ + bn + tcol;
    unsigned short* op = hwx + (size_t)z * MS + (size_t)gr0 * D_ + bn + tcol;
    #pragma unroll
    for (int h = 0; h < 2; ++h) {          // rows h*4 .. h*4+3 of the group
      float a4[4][8];
      #pragma unroll
      for (int i = 0; i < 4; ++i)
        unpack8(*reinterpret_cast<const uint4*>(
            &smem[(g8 + h * 4 + i) * 136 + tcol]), a4[i]);
      #pragma unroll
      for (int t = 0; t < 12; ++t) {       // absolute taps h*4 .. h*4+11
        float nf[8];
        unpack8(*reinterpret_cast<const uint4*>(
            np + (size_t)(h * 4 + t) * D_), nf);
        #pragma unroll
        for (int i = 0; i < 4; ++i) {
          if (t < i || t > i + 8) continue;
          float wv = wj[t - i];
          #pragma unroll
          for (int e = 0; e < 8; ++e) a4[i][e] += wv * nf[e];
        }
      }
      #pragma unroll
      for (int i = 0; i < 4; ++i) {
        uint4 o;
        o.x = pack2(a4[i][0], a4[i][1]); o.y = pack2(a4[i][2], a4[i][3]);
        o.z = pack2(a4[i][4], a4[i][5]); o.w = pack2(a4[i][6], a4[i][7]);
        *reinterpret_cast<uint4*>(op + (size_t)(h * 4 + i) * D_) = o;
      }
    }
  }
}

// ---------------------------------------------------------------------------
// Windowed attention, 4 consecutive rows per wave sharing a 13-row K/V
// window (r11-proven).
__global__ __launch_bounds__(256) void k_attn_window(
    const unsigned short* __restrict__ qkv,
    unsigned short* __restrict__ ctx)
{
  int wid = (blockIdx.x * 256 + threadIdx.x) >> 6;   // dir*2048 + b*256 + sg
  int lane = threadIdx.x & 63;
  int sg = wid & 255;
  int b = (wid >> 8) & 7;
  int dir = wid >> 11;
  int s0 = sg << 2;
  int i0 = s0 + WIDTH_;

  const size_t base = (size_t)b * S2_ * 3072 + dir * 1536;
  const int c0 = lane * 8;

  float qf[4][8];
  #pragma unroll
  for (int r = 0; r < 4; ++r)
    unpack8(*reinterpret_cast<const uint4*>(
        qkv + base + (size_t)(i0 + r) * 3072 + c0), qf[r]);

  float sc[4][10];
  float mx[4] = {-1e30f, -1e30f, -1e30f, -1e30f};
  #pragma unroll
  for (int t = 0; t < 13; ++t) {
    int j = (dir == 0) ? (i0 - 9 + t) : (i0 + t);
    bool ok = (j >= 0 && j < S2_);           // wave-uniform
    float kf[8];
    if (ok)
      unpack8(*reinterpret_cast<const uint4*>(
          qkv + base + (size_t)j * 3072 + 512 + c0), kf);
    #pragma unroll
    for (int r = 0; r < 4; ++r) {
      if (t < r || t > r + 9) continue;      // compile-time prune
      float sv = -1e30f;
      if (ok) {
        float p = qf[r][0] * kf[0];
        #pragma unroll
        for (int e = 1; e < 8; ++e) p += qf[r][e] * kf[e];
        p += __shfl_xor(p, 1);
        p += __shfl_xor(p, 2);
        p += __shfl_xor(p, 4);
        sv = p * 0.125f;
      }
      sc[r][t - r] = sv;
      mx[r] = fmaxf(mx[r], sv);
    }
  }

  float inv[4];
  #pragma unroll
  for (int r = 0; r < 4; ++r) {
    float den = 0.f;
    #pragma unroll
    for (int u = 0; u < 10; ++u) {
      sc[r][u] = (sc[r][u] > -1e29f) ? __expf(sc[r][u] - mx[r]) : 0.f;
      den += sc[r][u];
    }
    inv[r] = 1.f / den;
  }

  float acc[4][8];
  #pragma unroll
  for (int r = 0; r < 4; ++r)
    #pragma unroll
    for (int e = 0; e < 8; ++e) acc[r][e] = 0.f;

  #pragma unroll
  for (int t = 0; t < 13; ++t) {
    int j = (dir == 0) ? (i0 - 9 + t) : (i0 + t);
    bool ok = (j >= 0 && j < S2_);
    float vf[8];
    if (ok)
      unpack8(*reinterpret_cast<const uint4*>(
          qkv + base + (size_t)j * 3072 + 1024 + c0), vf);
    #pragma unroll
    for (int r = 0; r < 4; ++r) {
      if (t < r || t > r + 9) continue;
      if (ok) {
        float p = sc[r][t - r];
        #pragma unroll
        for (int e = 0; e < 8; ++e) acc[r][e] += p * vf[e];
      }
    }
  }

  #pragma unroll
  for (int r = 0; r < 4; ++r) {
    uint4 o;
    o.x = pack2(acc[r][0] * inv[r], acc[r][1] * inv[r]);
    o.y = pack2(acc[r][2] * inv[r], acc[r][3] * inv[r]);
    o.z = pack2(acc[r][4] * inv[r], acc[r][5] * inv[r]);
    o.w = pack2(acc[r][6] * inv[r], acc[r][7] * inv[r]);
    *reinterpret_cast<uint4*>(
        ctx + (((size_t)dir * B_ + b) * S_ + s0 + r) * D_ + c0) = o;
  }
}

// ---------------------------------------------------------------------------
extern "C" void kernel_launch(void* const* d_in, const int* in_sizes, int n_in,
                              void* d_out, int out_size, void* d_ws, size_t ws_size,
                              hipStream_t stream) {
  const float* x    = (const float*)d_in[0];
  const float* lW   = (const float*)d_in[1];
  const float* lb   = (const float*)d_in[2];
  const float* rW   = (const float*)d_in[3];
  const float* rb   = (const float*)d_in[4];
  const float* lpad = (const float*)d_in[5];
  const float* rpad = (const float*)d_in[6];
  const float* lw   = (const float*)d_in[7];
  const float* rw   = (const float*)d_in[8];
  const float* lhwW = (const float*)d_in[9];
  const float* lhwb = (const float*)d_in[10];
  const float* rhwW = (const float*)d_in[11];
  const float* rhwb = (const float*)d_in[12];
  float* out = (float*)d_out;
  unsigned short* ws = (unsigned short*)d_ws;

  const size_t NIN  = (size_t)B_ * S2_ * D_;       // 4,259,840
  const size_t NQKV = (size_t)B_ * S2_ * 3072;     // 25,559,040
  const size_t MS   = (size_t)B_ * S_ * D_;        // 4,194,304
  const size_t DD   = (size_t)D_ * D_;             // 262,144
  const size_t LHW  = (size_t)1024 * 512;          // 524,288

  unsigned short* nin   = ws;
  unsigned short* qkv   = nin + NIN;
  unsigned short* ctx   = qkv + NQKV;              // (2,B,S,D)
  unsigned short* hwx   = ctx + 2 * MS;            // (2,B,S,D)
  unsigned short* hwy   = hwx + 2 * MS;            // (2,B,S,D)
  unsigned short* WTall = hwy + 2 * MS;            // (3072,512)
  unsigned short* WTp   = WTall + 6 * DD;          // (2,512,512)
  unsigned short* hWT   = WTp + 2 * DD;            // (2,2,1024,512)
  float* qkvbias        = (float*)(hWT + 4 * LHW); // 3072 fp32

  // --- prep: 2 dispatches (split for per-kernel visibility) ---
  k_prep_w<<<4096, 256, 0, stream>>>(lW, rW, lhwW, rhwW, WTall, WTp, hWT);
  k_prep_x<<<2092, 256, 0, stream>>>(x, lpad, rpad, lb, rb, nin, qkvbias);

  const int MQ = B_ * S2_;   // 8320

  // --- fused QKV both sides: (8320 x 3072), 128^2 2-phase + XCD swizzle ---
  {
    dim3 g(3072 / 128, MQ / 128, 1);   // (24, 65) -> 1560 blocks, %8==0
    k_gemm_mfma<<<g, 256, 0, stream>>>(nin, WTall, qkvbias, qkv, MQ, 3072, D_);
  }

  // --- attention, both sides, 4 rows/wave ---
  k_attn_window<<<(2 * B_ * S_) / 16, 256, 0, stream>>>(qkv, ctx);

  // --- proj + fused rel-add, z-batched over side (128^2 kernel) ---
  {
    dim3 g(D_ / 128, (B_ * S_) / 128, 2);   // (4, 64, 2)
    k_gemm_proj<<<g, 256, 0, stream>>>(ctx, WTp, nin, lb + 3 * D_, rb + 3 * D_,
                                       lw, rw, hwx);
  }

  // --- highway layers: 256^2 8-phase + fused gate, z-batched over side ---
  {
    dim3 g(1024 / 256, (B_ * S_) / 256, 2);   // (4, 32, 2)
    k_gemm256<1><<<g, 512, 0, stream>>>(hwx, MS, hWT, 2 * LHW,
                                        lhwb, rhwb, hwy, nullptr,
                                        B_ * S_, 1024);
    k_gemm256<2><<<g, 512, 0, stream>>>(hwy, MS, hWT + LHW, 2 * LHW,
                                        lhwb + 1024, rhwb + 1024,
                                        nullptr, out, B_ * S_, 1024);
  }
}